// Round 12
// baseline (2414.245 us; speedup 1.0000x reference)
//
#include <hip/hip_runtime.h>
#include <hip/hip_bf16.h>

#define DD 2048
#define NF 24
#define NROWS 4096
#define VOCAB_N 32000
#define EPS_F 1.1920929e-07f

typedef __attribute__((ext_vector_type(8))) __bf16 bf16x8;
typedef __attribute__((ext_vector_type(4))) float f32x4;

__device__ __forceinline__ unsigned short f2bf(float f) {
  union { float f; unsigned int u; } v; v.f = f;
  unsigned int r = v.u + 0x7fffu + ((v.u >> 16) & 1u);  // RNE
  return (unsigned short)(r >> 16);
}
__device__ __forceinline__ float bf2f(unsigned short u) {
  union { unsigned int i; float f; } v; v.i = ((unsigned int)u) << 16; return v.f;
}

__device__ __forceinline__ void gload_lds16(const void* g, void* l) {
  __builtin_amdgcn_global_load_lds(
      (const __attribute__((address_space(1))) void*)g,
      (__attribute__((address_space(3))) void*)l, 16, 0, 0);
}

// ---------------- gather: h0 = bf16(embed[tok]); P0[row][0] = sumsq ----------------
__global__ __launch_bounds__(256) void k_gather(const int* __restrict__ tok,
                                                const float* __restrict__ embed,
                                                unsigned short* __restrict__ h0,
                                                float* __restrict__ p0) {
  const int row = blockIdx.x, tid = threadIdx.x;
  const int t = tok[row];
  const float4* s = (const float4*)(embed + (size_t)t * DD);
  const float4 a = s[tid], b = s[tid + 256];
  float ss = a.x * a.x + a.y * a.y + a.z * a.z + a.w * a.w +
             b.x * b.x + b.y * b.y + b.z * b.z + b.w * b.w;
#pragma unroll
  for (int m = 32; m; m >>= 1) ss += __shfl_xor(ss, m);
  __shared__ float part[4];
  if ((tid & 63) == 0) part[tid >> 6] = ss;
  __syncthreads();
  if (tid == 0) p0[(size_t)row * 8] = part[0] + part[1] + part[2] + part[3];
  ushort4 o0, o1;
  o0.x = f2bf(a.x); o0.y = f2bf(a.y); o0.z = f2bf(a.z); o0.w = f2bf(a.w);
  o1.x = f2bf(b.x); o1.y = f2bf(b.y); o1.z = f2bf(b.z); o1.w = f2bf(b.w);
  ushort4* d = (ushort4*)(h0 + (size_t)row * DD);
  d[tid] = o0;
  d[tid + 256] = o1;
}

// ---------------- W reconstruction via MFMA, norm_w folded (r11) ----------------
__global__ __launch_bounds__(256) void k_wrec(
    const float* __restrict__ hr, const float* __restrict__ hi,
    const float* __restrict__ kar, const float* __restrict__ kai,
    const float* __restrict__ kbr, const float* __restrict__ kbi,
    const float* __restrict__ scale, const float* __restrict__ nw,
    unsigned short* __restrict__ W) {
  __shared__ float KAR[16][132], KAI[16][132];
  __shared__ float KBR[16][68], KBI[16][68];
  __shared__ unsigned short Wt[128][72];
  const int tid = threadIdx.x;
  const int lane = tid & 63, w = tid >> 6;
  const int fr = lane & 15, g = lane >> 4;
  const int o0 = blockIdx.x * 128, i0 = blockIdx.y * 64;

  float hrg[2][4][4], hig[2][4][4];
#pragma unroll
  for (int of = 0; of < 2; ++of)
#pragma unroll
    for (int jj = 0; jj < 4; ++jj) {
      const size_t orow = (size_t)(o0 + w * 32 + of * 16 + g * 4 + jj) * DD + i0;
#pragma unroll
      for (int fi = 0; fi < 4; ++fi) {
        hrg[of][jj][fi] = hr[orow + fi * 16 + fr];
        hig[of][jj][fi] = hi[orow + fi * 16 + fr];
      }
    }

  const int sr = tid >> 4;
  const int sca = (tid & 15) * 8;
  const int scb = (tid & 15) * 4;
  const int rlo = (g & 1) * 8;

  for (int f = 0; f < NF; ++f) {
    __syncthreads();
    {
      const size_t ga = ((size_t)f * 16 + sr) * DD;
      *(float4*)&KAR[sr][sca]     = *(const float4*)&kar[ga + o0 + sca];
      *(float4*)&KAR[sr][sca + 4] = *(const float4*)&kar[ga + o0 + sca + 4];
      *(float4*)&KAI[sr][sca]     = *(const float4*)&kai[ga + o0 + sca];
      *(float4*)&KAI[sr][sca + 4] = *(const float4*)&kai[ga + o0 + sca + 4];
      *(float4*)&KBR[sr][scb]     = *(const float4*)&kbr[ga + i0 + scb];
      *(float4*)&KBI[sr][scb]     = *(const float4*)&kbi[ga + i0 + scb];
    }
    __syncthreads();
    bf16x8 aPr[2], aPi[2], bF[4];
#pragma unroll
    for (int of = 0; of < 2; ++of) {
      const int oc = w * 32 + of * 16 + fr;
      union { bf16x8 v; unsigned short u[8]; } pu, pv;
#pragma unroll
      for (int j = 0; j < 8; ++j) {
        const float ka = KAR[rlo + j][oc];
        const float kb = KAI[rlo + j][oc];
        pu.u[j] = f2bf((g < 2) ? ka : kb);
        pv.u[j] = f2bf((g < 2) ? kb : -ka);
      }
      aPr[of] = pu.v; aPi[of] = pv.v;
    }
#pragma unroll
    for (int fi = 0; fi < 4; ++fi) {
      const int ic = fi * 16 + fr;
      union { bf16x8 v; unsigned short u[8]; } pb;
#pragma unroll
      for (int j = 0; j < 8; ++j) {
        const float vr = KBR[rlo + j][ic];
        const float vi = KBI[rlo + j][ic];
        pb.u[j] = f2bf((g < 2) ? vr : vi);
      }
      bF[fi] = pb.v;
    }
    const float sc = scale[f];
    float nwv[4];
#pragma unroll
    for (int fi = 0; fi < 4; ++fi) nwv[fi] = nw[(size_t)f * DD + i0 + fi * 16 + fr];
#pragma unroll
    for (int of = 0; of < 2; ++of)
#pragma unroll
      for (int fi = 0; fi < 4; ++fi) {
        const f32x4 z = (f32x4){0.f, 0.f, 0.f, 0.f};
        const f32x4 cr = __builtin_amdgcn_mfma_f32_16x16x32_bf16(aPr[of], bF[fi], z, 0, 0, 0);
        const f32x4 ci = __builtin_amdgcn_mfma_f32_16x16x32_bf16(aPi[of], bF[fi], z, 0, 0, 0);
#pragma unroll
        for (int jj = 0; jj < 4; ++jj) {
          const float wv = (hrg[of][jj][fi] * cr[jj] - hig[of][jj][fi] * ci[jj]) * sc * nwv[fi];
          Wt[w * 32 + of * 16 + g * 4 + jj][fi * 16 + fr] = f2bf(wv);
        }
      }
    __syncthreads();
    {
      const int r = tid >> 1, hh = tid & 1;
      unsigned short* dst = W + ((size_t)f * DD + o0 + r) * DD + i0 + hh * 32;
#pragma unroll
      for (int qq = 0; qq < 4; ++qq)
        *(uint4*)(dst + qq * 8) = *(const uint4*)&Wt[r][hh * 32 + qq * 8];
    }
  }
}

// ---------------- k_gemmS: one-barrier/phase, ring-4, depth-2, fused norm ----------------
// BN=256, BK=32, 512 thr (8 waves, 2M x 4N); BM=128 (layers) or 256 (LM).
// Phase t: { STAGE(t+2 -> slot (t+2)&3) | ds_read slot t&3 | vmcnt(L or 0) |
//            BARRIER | lgkm0 | setprio1 MI*4 MFMA setprio0 }   -- NO barrier2.
// Overlap: between BAR(p) and BAR(p+1), wave v's MFMA(t) runs concurrently with
// wave w's reads(t+1)+STAGE(t+3) -> LDS and MFMA pipes both busy.
// Write-safety (the reason for ring-4/depth-2): STAGE(p) targets the slot last
// read as tile t-2; those reads were retired by each wave's lgkm0 in phase p-2,
// which precedes its BAR(p-1), which precedes every wave's STAGE(p). Formal.
// Read-safety: every wave's gate at p-1 (vmcnt(L)) retires its own tile-(t)
// loads; BAR(p-1) makes all portions visible before reads(t) at phase p.
// Tail: gate -> vmcnt(0) once staging stops. Swizzle key (row>>1)&3 on both
// sides (r3/r4-proven, 0 conflicts).
// ACT: 0 = residual add, 1 = residual add silu, 2 = LM store (C = inv * dot).
template <int ACT, int BM>
__global__ __launch_bounds__(512, 2) void k_gemmS(
    const unsigned short* __restrict__ Hin, const unsigned short* __restrict__ B,
    unsigned short* __restrict__ Hout, float* __restrict__ C, const int ldc,
    const int mtiles, const float* __restrict__ Pin, float* __restrict__ Pout) {
  constexpr int NT = DD / 32;            // 64 K-tiles
  constexpr int MI = BM / 32;            // 4 or 8
  constexpr int L = (BM == 256) ? 4 : 3; // gloads per tile
  __shared__ unsigned short lsA[4][BM * 32];
  __shared__ unsigned short lsB[4][256 * 32];
  __shared__ float invS[BM];
  __shared__ float rsum[128];
  const int tid = threadIdx.x;
  const int lane = tid & 63, wave = tid >> 6;
  const int wm = wave >> 2, wn = wave & 3;
  const int bid = blockIdx.x;
  const int swz = (bid & 7) * (gridDim.x >> 3) + (bid >> 3);
  const int t0 = (swz % mtiles) * BM;
  const int n0 = (swz / mtiles) * 256;
  const unsigned short* Ab = Hin + (size_t)t0 * DD;
  const unsigned short* Bb = B + (size_t)n0 * DD;
  const int fr = lane & 15, g = lane >> 4;
  const int srow = tid >> 2, sslot = tid & 3;

#define SSTG(slot, tile)                                                            \
  { _Pragma("unroll")                                                               \
    for (int l = 0; l < BM / 128; ++l) {                                            \
      const int rt = l * 128 + srow;                                                \
      const int ss = (sslot ^ ((rt >> 1) & 3)) << 3;                                \
      gload_lds16(Ab + (size_t)rt * DD + (tile) * 32 + ss,                          \
                  &lsA[slot][rt * 32 + sslot * 8]);                                 \
    }                                                                               \
    _Pragma("unroll")                                                               \
    for (int l = 0; l < 2; ++l) {                                                   \
      const int rt = l * 128 + srow;                                                \
      const int ss = (sslot ^ ((rt >> 1) & 3)) << 3;                                \
      gload_lds16(Bb + (size_t)rt * DD + (tile) * 32 + ss,                          \
                  &lsB[slot][rt * 32 + sslot * 8]);                                 \
    } }

  f32x4 acc[MI][4];
#pragma unroll
  for (int i = 0; i < MI; ++i)
#pragma unroll
    for (int j = 0; j < 4; ++j) acc[i][j] = (f32x4){0.f, 0.f, 0.f, 0.f};

  bf16x8 aF[MI], bF[4];

  // prologue: stage tiles 0,1; fused-norm inv factors; retire tile 0
  SSTG(0, 0);
  SSTG(1, 1);
  if (tid < BM) {
    const float* pr = Pin + (size_t)(t0 + tid) * 8;
    const float s = pr[0] + pr[1] + pr[2] + pr[3] + pr[4] + pr[5] + pr[6] + pr[7];
    invS[tid] = rsqrtf(s * (1.f / DD) + EPS_F);
  }
  asm volatile("s_waitcnt vmcnt(%0)" :: "i"(L) : "memory");
  __builtin_amdgcn_s_barrier();

  for (int t = 0; t < NT; ++t) {
    const int sc = t & 3, sp = (t + 2) & 3;
    const bool st = t + 2 < NT;
    if (st) SSTG(sp, t + 2);
#pragma unroll
    for (int mi = 0; mi < MI; ++mi) {
      const int r = wm * (BM / 2) + mi * 16 + fr;
      aF[mi] = *(const bf16x8*)&lsA[sc][r * 32 + ((g ^ ((r >> 1) & 3)) << 3)];
    }
#pragma unroll
    for (int ni = 0; ni < 4; ++ni) {
      const int r = wn * 64 + ni * 16 + fr;
      bF[ni] = *(const bf16x8*)&lsB[sc][r * 32 + ((g ^ ((r >> 1) & 3)) << 3)];
    }
    if (st) asm volatile("s_waitcnt vmcnt(%0)" :: "i"(L) : "memory");
    else    asm volatile("s_waitcnt vmcnt(0)" ::: "memory");
    __builtin_amdgcn_s_barrier();
    asm volatile("s_waitcnt lgkmcnt(0)" ::: "memory");
    __builtin_amdgcn_s_setprio(1);
#pragma unroll
    for (int mi = 0; mi < MI; ++mi)
#pragma unroll
      for (int ni = 0; ni < 4; ++ni)
        acc[mi][ni] = __builtin_amdgcn_mfma_f32_16x16x32_bf16(aF[mi], bF[ni],
                                                              acc[mi][ni], 0, 0, 0);
    __builtin_amdgcn_s_setprio(0);
  }
#undef SSTG

  if (ACT == 2) {
    // LM epilogue: C = inv[t] * dot
#pragma unroll
    for (int mi = 0; mi < MI; ++mi) {
#pragma unroll
      for (int ni = 0; ni < 4; ++ni) {
        const int ocol = n0 + wn * 64 + ni * 16 + fr;
#pragma unroll
        for (int j = 0; j < 4; ++j) {
          const int lr = wm * (BM / 2) + mi * 16 + g * 4 + j;
          C[(size_t)(t0 + lr) * ldc + ocol] = invS[lr] * acc[mi][ni][j];
        }
      }
    }
  } else {
    // layer epilogue: residual add + next-stage sumsq partial
    __syncthreads();
    if (tid < 128) rsum[tid] = 0.f;
    __syncthreads();
    const int panel = n0 >> 8;
#pragma unroll
    for (int mi = 0; mi < MI; ++mi) {
#pragma unroll
      for (int j = 0; j < 4; ++j) {
        const int lr = wm * 64 + mi * 16 + g * 4 + j;
        const float iv = invS[lr];
        float racc = 0.f;
#pragma unroll
        for (int ni = 0; ni < 4; ++ni) {
          const size_t idx = (size_t)(t0 + lr) * DD + (n0 + wn * 64 + ni * 16 + fr);
          const float v = acc[mi][ni][j] * iv;
          const float old = bf2f(Hin[idx]);
          float nv;
          if (ACT == 0) nv = old + v;
          else          nv = old + v / (1.f + __expf(-v));
          Hout[idx] = f2bf(nv);
          racc += nv * nv;
        }
        racc += __shfl_xor(racc, 1);
        racc += __shfl_xor(racc, 2);
        racc += __shfl_xor(racc, 4);
        racc += __shfl_xor(racc, 8);
        if (fr == 0) atomicAdd(&rsum[lr], racc);
      }
    }
    __syncthreads();
    if (tid < 128) Pout[(size_t)(t0 + tid) * 8 + panel] = rsum[tid];
  }
}

// ---------------- lm_bf16 = bf16(lm * fnw) ----------------
__global__ void k_cvt(const float* __restrict__ in, const float* __restrict__ fnw,
                      unsigned short* __restrict__ out, int n4) {
  int i = blockIdx.x * blockDim.x + threadIdx.x;
  const int stride = gridDim.x * blockDim.x;
  for (; i < n4; i += stride) {
    const float4 v = ((const float4*)in)[i];
    const float4 w = ((const float4*)fnw)[i & 511];  // DD/4 = 512
    ushort4 o;
    o.x = f2bf(v.x * w.x); o.y = f2bf(v.y * w.y);
    o.z = f2bf(v.z * w.z); o.w = f2bf(v.w * w.w);
    ((ushort4*)out)[i] = o;
  }
}

extern "C" void kernel_launch(void* const* d_in, const int* in_sizes, int n_in,
                              void* d_out, int out_size, void* d_ws, size_t ws_size,
                              hipStream_t stream) {
  (void)in_sizes; (void)n_in; (void)out_size; (void)ws_size;
  const int* tokens = (const int*)d_in[0];
  const float* hr = (const float*)d_in[1];
  const float* hi = (const float*)d_in[2];
  const float* kar = (const float*)d_in[3];
  const float* kai = (const float*)d_in[4];
  const float* kbr = (const float*)d_in[5];
  const float* kbi = (const float*)d_in[6];
  const float* lscale = (const float*)d_in[7];
  const float* norm_w = (const float*)d_in[8];
  const float* embed = (const float*)d_in[9];
  const float* lm = (const float*)d_in[10];
  const float* fnw = (const float*)d_in[11];
  float* out = (float*)d_out;
  char* ws = (char*)d_ws;

  // ws: W' 192MB | P0,P1 (4096x8 f32 each) | hA bf16 16.7MB.
  // hB = first 16.7MB of d_out (dead before LM writes d_out; parity: 24 swaps).
  // lmb overlays W' (dead after last layer). Norm fused: W' carries norm_w,
  // lmb carries fnw, 1/rms applied in GEMM epilogues via P ping-pong.
  unsigned short* W = (unsigned short*)ws;
  float* P0 = (float*)(ws + 201326592);
  float* P1 = P0 + (size_t)NROWS * 8;
  unsigned short* hA = (unsigned short*)(ws + 201326592 + 262144);
  unsigned short* hB = (unsigned short*)d_out;
  unsigned short* lmb = W;

  hipMemsetAsync(P0, 0, (size_t)NROWS * 8 * sizeof(float), stream);
  k_gather<<<NROWS, 256, 0, stream>>>(tokens, embed, hA, P0);
  k_wrec<<<dim3(16, 32), 256, 0, stream>>>(hr, hi, kar, kai, kbr, kbi, lscale,
                                           norm_w, W);
  const unsigned short* cin = hA;
  unsigned short* cout = hB;
  const float* pin = P0;
  float* pout = P1;
  for (int l = 0; l < 12; ++l) {
    k_gemmS<0, 128><<<256, 512, 0, stream>>>(cin, W + (size_t)(2 * l) * DD * DD,
                                             cout, nullptr, DD, 32, pin, pout);
    { const unsigned short* tc = cin; cin = cout; cout = (unsigned short*)tc;
      const float* tp = pin; pin = pout; pout = (float*)tp; }
    k_gemmS<1, 128><<<256, 512, 0, stream>>>(cin, W + (size_t)(2 * l + 1) * DD * DD,
                                             cout, nullptr, DD, 32, pin, pout);
    { const unsigned short* tc = cin; cin = cout; cout = (unsigned short*)tc;
      const float* tp = pin; pin = pout; pout = (float*)tp; }
  }
  // after 24 swaps: cin == hA, pin == P0
  k_cvt<<<2048, 256, 0, stream>>>(lm, fnw, lmb, VOCAB_N * DD / 4);
  k_gemmS<2, 256><<<2000, 512, 0, stream>>>(cin, lmb, nullptr, out, VOCAB_N, 16,
                                            pin, nullptr);
}

// Round 13
// 1976.800 us; speedup vs baseline: 1.2213x; 1.2213x over previous
//
#include <hip/hip_runtime.h>
#include <hip/hip_bf16.h>

#define DD 2048
#define NF 24
#define NROWS 4096
#define VOCAB_N 32000
#define EPS_F 1.1920929e-07f

typedef __attribute__((ext_vector_type(8))) __bf16 bf16x8;
typedef __attribute__((ext_vector_type(4))) float f32x4;

__device__ __forceinline__ unsigned short f2bf(float f) {
  union { float f; unsigned int u; } v; v.f = f;
  unsigned int r = v.u + 0x7fffu + ((v.u >> 16) & 1u);  // RNE
  return (unsigned short)(r >> 16);
}
__device__ __forceinline__ float bf2f(unsigned short u) {
  union { unsigned int i; float f; } v; v.i = ((unsigned int)u) << 16; return v.f;
}

__device__ __forceinline__ void gload_lds16(const void* g, void* l) {
  __builtin_amdgcn_global_load_lds(
      (const __attribute__((address_space(1))) void*)g,
      (__attribute__((address_space(3))) void*)l, 16, 0, 0);
}

// ---------------- gather: h0 = bf16(embed[tok]); P0[row][0] = sumsq ----------------
__global__ __launch_bounds__(256) void k_gather(const int* __restrict__ tok,
                                                const float* __restrict__ embed,
                                                unsigned short* __restrict__ h0,
                                                float* __restrict__ p0) {
  const int row = blockIdx.x, tid = threadIdx.x;
  const int t = tok[row];
  const float4* s = (const float4*)(embed + (size_t)t * DD);
  const float4 a = s[tid], b = s[tid + 256];
  float ss = a.x * a.x + a.y * a.y + a.z * a.z + a.w * a.w +
             b.x * b.x + b.y * b.y + b.z * b.z + b.w * b.w;
#pragma unroll
  for (int m = 32; m; m >>= 1) ss += __shfl_xor(ss, m);
  __shared__ float part[4];
  if ((tid & 63) == 0) part[tid >> 6] = ss;
  __syncthreads();
  if (tid == 0) p0[(size_t)row * 8] = part[0] + part[1] + part[2] + part[3];
  ushort4 o0, o1;
  o0.x = f2bf(a.x); o0.y = f2bf(a.y); o0.z = f2bf(a.z); o0.w = f2bf(a.w);
  o1.x = f2bf(b.x); o1.y = f2bf(b.y); o1.z = f2bf(b.z); o1.w = f2bf(b.w);
  ushort4* d = (ushort4*)(h0 + (size_t)row * DD);
  d[tid] = o0;
  d[tid + 256] = o1;
}

// ---------------- W reconstruction via MFMA, norm_w folded (r11) ----------------
__global__ __launch_bounds__(256) void k_wrec(
    const float* __restrict__ hr, const float* __restrict__ hi,
    const float* __restrict__ kar, const float* __restrict__ kai,
    const float* __restrict__ kbr, const float* __restrict__ kbi,
    const float* __restrict__ scale, const float* __restrict__ nw,
    unsigned short* __restrict__ W) {
  __shared__ float KAR[16][132], KAI[16][132];
  __shared__ float KBR[16][68], KBI[16][68];
  __shared__ unsigned short Wt[128][72];
  const int tid = threadIdx.x;
  const int lane = tid & 63, w = tid >> 6;
  const int fr = lane & 15, g = lane >> 4;
  const int o0 = blockIdx.x * 128, i0 = blockIdx.y * 64;

  float hrg[2][4][4], hig[2][4][4];
#pragma unroll
  for (int of = 0; of < 2; ++of)
#pragma unroll
    for (int jj = 0; jj < 4; ++jj) {
      const size_t orow = (size_t)(o0 + w * 32 + of * 16 + g * 4 + jj) * DD + i0;
#pragma unroll
      for (int fi = 0; fi < 4; ++fi) {
        hrg[of][jj][fi] = hr[orow + fi * 16 + fr];
        hig[of][jj][fi] = hi[orow + fi * 16 + fr];
      }
    }

  const int sr = tid >> 4;
  const int sca = (tid & 15) * 8;
  const int scb = (tid & 15) * 4;
  const int rlo = (g & 1) * 8;

  for (int f = 0; f < NF; ++f) {
    __syncthreads();
    {
      const size_t ga = ((size_t)f * 16 + sr) * DD;
      *(float4*)&KAR[sr][sca]     = *(const float4*)&kar[ga + o0 + sca];
      *(float4*)&KAR[sr][sca + 4] = *(const float4*)&kar[ga + o0 + sca + 4];
      *(float4*)&KAI[sr][sca]     = *(const float4*)&kai[ga + o0 + sca];
      *(float4*)&KAI[sr][sca + 4] = *(const float4*)&kai[ga + o0 + sca + 4];
      *(float4*)&KBR[sr][scb]     = *(const float4*)&kbr[ga + i0 + scb];
      *(float4*)&KBI[sr][scb]     = *(const float4*)&kbi[ga + i0 + scb];
    }
    __syncthreads();
    bf16x8 aPr[2], aPi[2], bF[4];
#pragma unroll
    for (int of = 0; of < 2; ++of) {
      const int oc = w * 32 + of * 16 + fr;
      union { bf16x8 v; unsigned short u[8]; } pu, pv;
#pragma unroll
      for (int j = 0; j < 8; ++j) {
        const float ka = KAR[rlo + j][oc];
        const float kb = KAI[rlo + j][oc];
        pu.u[j] = f2bf((g < 2) ? ka : kb);
        pv.u[j] = f2bf((g < 2) ? kb : -ka);
      }
      aPr[of] = pu.v; aPi[of] = pv.v;
    }
#pragma unroll
    for (int fi = 0; fi < 4; ++fi) {
      const int ic = fi * 16 + fr;
      union { bf16x8 v; unsigned short u[8]; } pb;
#pragma unroll
      for (int j = 0; j < 8; ++j) {
        const float vr = KBR[rlo + j][ic];
        const float vi = KBI[rlo + j][ic];
        pb.u[j] = f2bf((g < 2) ? vr : vi);
      }
      bF[fi] = pb.v;
    }
    const float sc = scale[f];
    float nwv[4];
#pragma unroll
    for (int fi = 0; fi < 4; ++fi) nwv[fi] = nw[(size_t)f * DD + i0 + fi * 16 + fr];
#pragma unroll
    for (int of = 0; of < 2; ++of)
#pragma unroll
      for (int fi = 0; fi < 4; ++fi) {
        const f32x4 z = (f32x4){0.f, 0.f, 0.f, 0.f};
        const f32x4 cr = __builtin_amdgcn_mfma_f32_16x16x32_bf16(aPr[of], bF[fi], z, 0, 0, 0);
        const f32x4 ci = __builtin_amdgcn_mfma_f32_16x16x32_bf16(aPi[of], bF[fi], z, 0, 0, 0);
#pragma unroll
        for (int jj = 0; jj < 4; ++jj) {
          const float wv = (hrg[of][jj][fi] * cr[jj] - hig[of][jj][fi] * ci[jj]) * sc * nwv[fi];
          Wt[w * 32 + of * 16 + g * 4 + jj][fi * 16 + fr] = f2bf(wv);
        }
      }
    __syncthreads();
    {
      const int r = tid >> 1, hh = tid & 1;
      unsigned short* dst = W + ((size_t)f * DD + o0 + r) * DD + i0 + hh * 32;
#pragma unroll
      for (int qq = 0; qq < 4; ++qq)
        *(uint4*)(dst + qq * 8) = *(const uint4*)&Wt[r][hh * 32 + qq * 8];
    }
  }
}

// ---------------- layer GEMM: ring-3 (r8 schedule) + fused norm (r11) ----------------
template <int ACT>
__global__ __launch_bounds__(512, 2) void k_gemmL(const unsigned short* __restrict__ Hin,
                                                  const unsigned short* __restrict__ B,
                                                  unsigned short* __restrict__ Hout,
                                                  const float* __restrict__ Pin,
                                                  float* __restrict__ Pout) {
  constexpr int NTILE = DD / 64;  // 32
  __shared__ unsigned short lsA[3][8192];    // [slot][128 rows][64 k]
  __shared__ unsigned short lsB[3][16384];   // [slot][256 rows][64 k]
  __shared__ float invS[128];
  __shared__ float rsum[128];
  const int tid = threadIdx.x;
  const int lane = tid & 63, wave = tid >> 6;
  const int wm = wave >> 2, wn = wave & 3;
  const int bid = blockIdx.x;
  const int swz = (bid & 7) * 32 + (bid >> 3);   // 256 blocks: XCD-contig
  const int t0 = (swz & 31) * 128;
  const int n0 = (swz >> 5) * 256;
  const unsigned short* Ab = Hin + (size_t)t0 * DD;
  const unsigned short* Bb = B + (size_t)n0 * DD;
  const int fr = lane & 15, g = lane >> 4;
  const int srow8 = tid >> 3, sslot = tid & 7;

#define LSTG_A(slot, tile)                                                          \
  { _Pragma("unroll")                                                               \
    for (int l = 0; l < 2; ++l) {                                                   \
      const int rt = l * 64 + srow8;                                                \
      gload_lds16(Ab + (size_t)rt * DD + (tile) * 64 + ((sslot ^ (rt & 7)) << 3),   \
                  &lsA[slot][rt * 64 + sslot * 8]);                                 \
    } }
#define LSTG_B(slot, h, tile)                                                       \
  { _Pragma("unroll")                                                               \
    for (int l = 0; l < 2; ++l) {                                                   \
      const int rt = (h) * 128 + l * 64 + srow8;                                    \
      gload_lds16(Bb + (size_t)rt * DD + (tile) * 64 + ((sslot ^ (rt & 7)) << 3),   \
                  &lsB[slot][rt * 64 + sslot * 8]);                                 \
    } }
#define LRD_A(slot, mi, ks)                                                         \
  (*(const bf16x8*)&lsA[slot][(wm * 64 + (mi) * 16 + fr) * 64 +                     \
                              ((((ks) * 4 + g) ^ ((wm * 64 + (mi) * 16 + fr) & 7)) << 3)])
#define LRD_B(slot, ni, ks)                                                         \
  (*(const bf16x8*)&lsB[slot][(wn * 64 + (ni) * 16 + fr) * 64 +                     \
                              ((((ks) * 4 + g) ^ ((wn * 64 + (ni) * 16 + fr) & 7)) << 3)])

  f32x4 acc[4][4];
#pragma unroll
  for (int i = 0; i < 4; ++i)
#pragma unroll
    for (int j = 0; j < 4; ++j) acc[i][j] = (f32x4){0.f, 0.f, 0.f, 0.f};

  bf16x8 aF[4][2], bF[2][2];

#define LTILE(t, sc, sp)                                                            \
  {                                                                                 \
    const bool st = (t) + 2 < NTILE;                                                \
    /* ---- phase nh0 ---- */                                                       \
    _Pragma("unroll")                                                               \
    for (int mi = 0; mi < 4; ++mi) { _Pragma("unroll")                              \
      for (int ks = 0; ks < 2; ++ks) aF[mi][ks] = LRD_A(sc, mi, ks); }              \
    _Pragma("unroll")                                                               \
    for (int q = 0; q < 2; ++q) { _Pragma("unroll")                                 \
      for (int ks = 0; ks < 2; ++ks) bF[q][ks] = LRD_B(sc, q, ks); }                \
    if (st) { LSTG_A(sp, (t) + 2); LSTG_B(sp, 0, (t) + 2); }                        \
    __builtin_amdgcn_s_barrier();                                                   \
    asm volatile("s_waitcnt lgkmcnt(0)" ::: "memory");                              \
    __builtin_amdgcn_s_setprio(1);                                                  \
    _Pragma("unroll")                                                               \
    for (int ks = 0; ks < 2; ++ks) { _Pragma("unroll")                              \
      for (int mi = 0; mi < 4; ++mi) { _Pragma("unroll")                            \
        for (int q = 0; q < 2; ++q)                                                 \
          acc[mi][q] = __builtin_amdgcn_mfma_f32_16x16x32_bf16(                     \
              aF[mi][ks], bF[q][ks], acc[mi][q], 0, 0, 0); } }                      \
    __builtin_amdgcn_s_setprio(0);                                                  \
    __builtin_amdgcn_s_barrier();                                                   \
    /* ---- phase nh1 ---- */                                                       \
    _Pragma("unroll")                                                               \
    for (int q = 0; q < 2; ++q) { _Pragma("unroll")                                 \
      for (int ks = 0; ks < 2; ++ks) bF[q][ks] = LRD_B(sc, 2 + q, ks); }            \
    if (st) LSTG_B(sp, 1, (t) + 2);                                                 \
    if (st) asm volatile("s_waitcnt vmcnt(6)" ::: "memory");                        \
    else    asm volatile("s_waitcnt vmcnt(0)" ::: "memory");                        \
    __builtin_amdgcn_s_barrier();                                                   \
    asm volatile("s_waitcnt lgkmcnt(0)" ::: "memory");                              \
    __builtin_amdgcn_s_setprio(1);                                                  \
    _Pragma("unroll")                                                               \
    for (int ks = 0; ks < 2; ++ks) { _Pragma("unroll")                              \
      for (int mi = 0; mi < 4; ++mi) { _Pragma("unroll")                            \
        for (int q = 0; q < 2; ++q)                                                 \
          acc[mi][2 + q] = __builtin_amdgcn_mfma_f32_16x16x32_bf16(                 \
              aF[mi][ks], bF[q][ks], acc[mi][2 + q], 0, 0, 0); } }                  \
    __builtin_amdgcn_s_setprio(0);                                                  \
    __builtin_amdgcn_s_barrier();                                                   \
  }

  LSTG_A(0, 0); LSTG_B(0, 0, 0); LSTG_B(0, 1, 0);
  LSTG_A(1, 1); LSTG_B(1, 0, 1); LSTG_B(1, 1, 1);
  // fused-norm prologue: inv per row from 8 panel partials
  if (tid < 128) {
    const float* pr = Pin + (size_t)(t0 + tid) * 8;
    const float s = pr[0] + pr[1] + pr[2] + pr[3] + pr[4] + pr[5] + pr[6] + pr[7];
    invS[tid] = rsqrtf(s * (1.f / DD) + EPS_F);
  }
  asm volatile("s_waitcnt vmcnt(6)" ::: "memory");
  __builtin_amdgcn_s_barrier();

  for (int tb = 0; tb < 30; tb += 3) {
    LTILE(tb, 0, 2);
    LTILE(tb + 1, 1, 0);
    LTILE(tb + 2, 2, 1);
  }
  LTILE(30, 0, 2);
  LTILE(31, 1, 0);
#undef LTILE
#undef LRD_A
#undef LRD_B
#undef LSTG_A
#undef LSTG_B

  // epilogue: apply inv, residual-add into Hout, per-row sumsq partial -> Pout
  __syncthreads();
  if (tid < 128) rsum[tid] = 0.f;
  __syncthreads();
  const int panel = n0 >> 8;
#pragma unroll
  for (int mi = 0; mi < 4; ++mi) {
#pragma unroll
    for (int j = 0; j < 4; ++j) {
      const int lr = wm * 64 + mi * 16 + g * 4 + j;
      const float iv = invS[lr];
      float racc = 0.f;
#pragma unroll
      for (int ni = 0; ni < 4; ++ni) {
        const size_t idx = (size_t)(t0 + lr) * DD + (n0 + wn * 64 + ni * 16 + fr);
        const float v = acc[mi][ni][j] * iv;
        const float old = bf2f(Hin[idx]);
        float nv;
        if (ACT == 0) nv = old + v;
        else          nv = old + v / (1.f + __expf(-v));
        Hout[idx] = f2bf(nv);
        racc += nv * nv;
      }
      racc += __shfl_xor(racc, 1);
      racc += __shfl_xor(racc, 2);
      racc += __shfl_xor(racc, 4);
      racc += __shfl_xor(racc, 8);
      if (fr == 0) atomicAdd(&rsum[lr], racc);
    }
  }
  __syncthreads();
  if (tid < 128) Pout[(size_t)(t0 + tid) * 8 + panel] = rsum[tid];
}

// ---------------- 8-phase GEMM for LM head (r7 schedule + inv scale + nt stores) ----------------
// C[t][n] = inv[t] * sum_k A[t][k]*B[n][k]; C written NON-TEMPORAL (write-once
// stream; bypass L2/L3 so the 512MB logit stream stops evicting B/A operands).
template <int BM>
__global__ __launch_bounds__(512, 2) void k_gemm8(const unsigned short* __restrict__ A,
                                                  const unsigned short* __restrict__ B,
                                                  float* __restrict__ C, const int ldc,
                                                  const int mtiles,
                                                  const float* __restrict__ Pin) {
  constexpr int HALF = BM / 2;
  constexpr int MI = BM / 32;
  constexpr int MQ = MI / 2;
  constexpr int A_LOADS = HALF / 64;
  constexpr int NTILE = DD / 64;
  constexpr int NITER = NTILE / 2;

  __shared__ unsigned short lsA[2][BM * 64];
  __shared__ unsigned short lsB[2][256 * 64];
  __shared__ float invS[BM];

  const int tid = threadIdx.x;
  const int lane = tid & 63, wave = tid >> 6;
  const int wm = wave >> 2, wn = wave & 3;
  const int bid = blockIdx.x;
  const int swz = (bid & 7) * (gridDim.x >> 3) + (bid >> 3);
  const int t0 = (swz % mtiles) * BM;
  const int n0 = (swz / mtiles) * 256;
  const unsigned short* Ab = A + (size_t)t0 * DD;
  const unsigned short* Bb = B + (size_t)n0 * DD;
  const int fr = lane & 15, g = lane >> 4;
  const int srow8 = tid >> 3, sslot = tid & 7;

#define STG_A(buf, h, tile)                                                         \
  { _Pragma("unroll")                                                               \
    for (int l = 0; l < A_LOADS; ++l) {                                             \
      const int rt = (h) * HALF + l * 64 + srow8;                                   \
      gload_lds16(Ab + (size_t)rt * DD + (tile) * 64 + ((sslot ^ (rt & 7)) << 3),   \
                  &lsA[buf][rt * 64 + sslot * 8]);                                  \
    } }
#define STG_B(buf, h, tile)                                                         \
  { _Pragma("unroll")                                                               \
    for (int l = 0; l < 2; ++l) {                                                   \
      const int rt = (h) * 128 + l * 64 + srow8;                                    \
      gload_lds16(Bb + (size_t)rt * DD + (tile) * 64 + ((sslot ^ (rt & 7)) << 3),   \
                  &lsB[buf][rt * 64 + sslot * 8]);                                  \
    } }
#define VM_G3()                                                                     \
  { if constexpr (BM == 256) asm volatile("s_waitcnt vmcnt(6)" ::: "memory");       \
    else                     asm volatile("s_waitcnt vmcnt(5)" ::: "memory"); }
#define VM_G7()                                                                     \
  { if constexpr (BM == 256) asm volatile("s_waitcnt vmcnt(8)" ::: "memory");       \
    else                     asm volatile("s_waitcnt vmcnt(6)" ::: "memory"); }
#define VM_PRO()                                                                    \
  { if constexpr (BM == 256) asm volatile("s_waitcnt vmcnt(8)" ::: "memory");       \
    else                     asm volatile("s_waitcnt vmcnt(6)" ::: "memory"); }
#define VM_ZERO() asm volatile("s_waitcnt vmcnt(0)" ::: "memory")

  f32x4 acc[MI][4];
#pragma unroll
  for (int i = 0; i < MI; ++i)
#pragma unroll
    for (int j = 0; j < 4; ++j) acc[i][j] = (f32x4){0.f, 0.f, 0.f, 0.f};

  bf16x8 aF[MQ][2];
  bf16x8 bF[2][2][2];

#define RD_A(buf, mi, ks)                                                           \
  (*(const bf16x8*)&lsA[buf][(wm * HALF + (mi) * 16 + fr) * 64 +                    \
                             ((((ks) * 4 + g) ^ ((wm * HALF + (mi) * 16 + fr) & 7)) << 3)])
#define RD_B(buf, ni, ks)                                                           \
  (*(const bf16x8*)&lsB[buf][(wn * 64 + (ni) * 16 + fr) * 64 +                      \
                             ((((ks) * 4 + g) ^ ((wn * 64 + (ni) * 16 + fr) & 7)) << 3)])

#define PHASE(buf, mh, nh, LA, LB, STAGES, VMK)                                     \
  {                                                                                 \
    if (LA) { _Pragma("unroll")                                                     \
      for (int q = 0; q < MQ; ++q) { _Pragma("unroll")                              \
        for (int ks = 0; ks < 2; ++ks) aF[q][ks] = RD_A(buf, (mh) * MQ + q, ks); } }\
    if (LB) { _Pragma("unroll")                                                     \
      for (int q = 0; q < 2; ++q) { _Pragma("unroll")                               \
        for (int ks = 0; ks < 2; ++ks) bF[nh][q][ks] = RD_B(buf, (nh) * 2 + q, ks); } } \
    STAGES;                                                                         \
    VMK;                                                                            \
    __builtin_amdgcn_s_barrier();                                                   \
    asm volatile("s_waitcnt lgkmcnt(0)" ::: "memory");                              \
    __builtin_amdgcn_s_setprio(1);                                                  \
    _Pragma("unroll")                                                               \
    for (int ks = 0; ks < 2; ++ks) { _Pragma("unroll")                              \
      for (int q = 0; q < MQ; ++q) { _Pragma("unroll")                              \
        for (int nq = 0; nq < 2; ++nq)                                              \
          acc[(mh) * MQ + q][(nh) * 2 + nq] = __builtin_amdgcn_mfma_f32_16x16x32_bf16( \
              aF[q][ks], bF[nh][nq][ks], acc[(mh) * MQ + q][(nh) * 2 + nq], 0, 0, 0); } } \
    __builtin_amdgcn_s_setprio(0);                                                  \
    __builtin_amdgcn_s_barrier();                                                   \
  }

  STG_B(0, 0, 0); STG_B(0, 1, 0); STG_A(0, 0, 0); STG_A(0, 1, 0);
  STG_B(1, 0, 1); STG_B(1, 1, 1); STG_A(1, 0, 1); STG_A(1, 1, 1);
  if (tid < BM) {
    const float* pr = Pin + (size_t)(t0 + tid) * 8;
    const float s = pr[0] + pr[1] + pr[2] + pr[3] + pr[4] + pr[5] + pr[6] + pr[7];
    invS[tid] = rsqrtf(s * (1.f / DD) + EPS_F);
  }
  VM_PRO();
  __builtin_amdgcn_s_barrier();

  for (int i = 0; i < NITER; ++i) {
    const int T2 = 2 * i + 2, T3 = 2 * i + 3;
    const bool s2 = T2 < NTILE, s3 = T3 < NTILE;
    PHASE(0, 0, 0, true,  true,  {}, {});
    PHASE(0, 0, 1, false, true,  {}, {});
    PHASE(0, 1, 1, true,  false, { if (s2) { STG_B(0, 0, T2); STG_B(0, 1, T2); } }, {});
    PHASE(0, 1, 0, false, false, { if (s2) STG_A(0, 0, T2); },
          { if (s2) VM_G3() else VM_ZERO(); });
    PHASE(1, 0, 0, true,  true,  { if (s2) STG_A(0, 1, T2); }, {});
    PHASE(1, 0, 1, false, true,  {}, {});
    PHASE(1, 1, 1, true,  false, { if (s3) { STG_B(1, 0, T3); STG_B(1, 1, T3); } }, {});
    PHASE(1, 1, 0, false, false, { if (s3) { STG_A(1, 0, T3); STG_A(1, 1, T3); } },
          { if (s3) VM_G7() else VM_ZERO(); });
  }
#undef PHASE
#undef RD_A
#undef RD_B
#undef STG_A
#undef STG_B
#undef VM_G3
#undef VM_G7
#undef VM_PRO
#undef VM_ZERO

#pragma unroll
  for (int mi = 0; mi < MI; ++mi) {
#pragma unroll
    for (int ni = 0; ni < 4; ++ni) {
      const int ocol = n0 + wn * 64 + ni * 16 + fr;
#pragma unroll
      for (int j = 0; j < 4; ++j) {
        const int lr = wm * HALF + mi * 16 + g * 4 + j;
        const size_t idx = (size_t)(t0 + lr) * ldc + ocol;
        __builtin_nontemporal_store(invS[lr] * acc[mi][ni][j], &C[idx]);
      }
    }
  }
}

// ---------------- lm_bf16 = bf16(lm * fnw) ----------------
__global__ void k_cvt(const float* __restrict__ in, const float* __restrict__ fnw,
                      unsigned short* __restrict__ out, int n4) {
  int i = blockIdx.x * blockDim.x + threadIdx.x;
  const int stride = gridDim.x * blockDim.x;
  for (; i < n4; i += stride) {
    const float4 v = ((const float4*)in)[i];
    const float4 w = ((const float4*)fnw)[i & 511];  // DD/4 = 512
    ushort4 o;
    o.x = f2bf(v.x * w.x); o.y = f2bf(v.y * w.y);
    o.z = f2bf(v.z * w.z); o.w = f2bf(v.w * w.w);
    ((ushort4*)out)[i] = o;
  }
}

extern "C" void kernel_launch(void* const* d_in, const int* in_sizes, int n_in,
                              void* d_out, int out_size, void* d_ws, size_t ws_size,
                              hipStream_t stream) {
  (void)in_sizes; (void)n_in; (void)out_size; (void)ws_size;
  const int* tokens = (const int*)d_in[0];
  const float* hr = (const float*)d_in[1];
  const float* hi = (const float*)d_in[2];
  const float* kar = (const float*)d_in[3];
  const float* kai = (const float*)d_in[4];
  const float* kbr = (const float*)d_in[5];
  const float* kbi = (const float*)d_in[6];
  const float* lscale = (const float*)d_in[7];
  const float* norm_w = (const float*)d_in[8];
  const float* embed = (const float*)d_in[9];
  const float* lm = (const float*)d_in[10];
  const float* fnw = (const float*)d_in[11];
  float* out = (float*)d_out;
  char* ws = (char*)d_ws;

  // ws: W' 192MB | P0,P1 (4096x8 f32 each) | hA bf16 16.7MB.
  // hB = first 16.7MB of d_out (dead before LM writes d_out; parity: 24 swaps).
  // lmb overlays W' (dead after last layer). Norm fused: W' carries norm_w,
  // lmb carries fnw, 1/rms applied in GEMM epilogues via P ping-pong.
  unsigned short* W = (unsigned short*)ws;
  float* P0 = (float*)(ws + 201326592);
  float* P1 = P0 + (size_t)NROWS * 8;
  unsigned short* hA = (unsigned short*)(ws + 201326592 + 262144);
  unsigned short* hB = (unsigned short*)d_out;
  unsigned short* lmb = W;

  hipMemsetAsync(P0, 0, (size_t)NROWS * 8 * sizeof(float), stream);
  k_gather<<<NROWS, 256, 0, stream>>>(tokens, embed, hA, P0);
  k_wrec<<<dim3(16, 32), 256, 0, stream>>>(hr, hi, kar, kai, kbr, kbi, lscale,
                                           norm_w, W);
  const unsigned short* cin = hA;
  unsigned short* cout = hB;
  const float* pin = P0;
  float* pout = P1;
  for (int l = 0; l < 12; ++l) {
    k_gemmL<0><<<256, 512, 0, stream>>>(cin, W + (size_t)(2 * l) * DD * DD, cout, pin, pout);
    { const unsigned short* tc = cin; cin = cout; cout = (unsigned short*)tc;
      const float* tp = pin; pin = pout; pout = (float*)tp; }
    k_gemmL<1><<<256, 512, 0, stream>>>(cin, W + (size_t)(2 * l + 1) * DD * DD, cout, pin, pout);
    { const unsigned short* tc = cin; cin = cout; cout = (unsigned short*)tc;
      const float* tp = pin; pin = pout; pout = (float*)tp; }
  }
  // after 24 swaps: cin == hA, pin == P0
  k_cvt<<<2048, 256, 0, stream>>>(lm, fnw, lmb, VOCAB_N * DD / 4);
  k_gemm8<256><<<2000, 512, 0, stream>>>(cin, lmb, out, VOCAB_N, 16, pin);
}

// Round 14
// 1913.948 us; speedup vs baseline: 1.2614x; 1.0328x over previous
//
#include <hip/hip_runtime.h>
#include <hip/hip_bf16.h>

#define DD 2048
#define NF 24
#define NROWS 4096
#define VOCAB_N 32000
#define EPS_F 1.1920929e-07f

typedef __attribute__((ext_vector_type(8))) __bf16 bf16x8;
typedef __attribute__((ext_vector_type(4))) float f32x4;

__device__ __forceinline__ unsigned short f2bf(float f) {
  union { float f; unsigned int u; } v; v.f = f;
  unsigned int r = v.u + 0x7fffu + ((v.u >> 16) & 1u);  // RNE
  return (unsigned short)(r >> 16);
}
__device__ __forceinline__ float bf2f(unsigned short u) {
  union { unsigned int i; float f; } v; v.i = ((unsigned int)u) << 16; return v.f;
}

__device__ __forceinline__ void gload_lds16(const void* g, void* l) {
  __builtin_amdgcn_global_load_lds(
      (const __attribute__((address_space(1))) void*)g,
      (__attribute__((address_space(3))) void*)l, 16, 0, 0);
}

// ---------------- gather: h0 = bf16(embed[tok]); P0[row][0] = sumsq ----------------
__global__ __launch_bounds__(256) void k_gather(const int* __restrict__ tok,
                                                const float* __restrict__ embed,
                                                unsigned short* __restrict__ h0,
                                                float* __restrict__ p0) {
  const int row = blockIdx.x, tid = threadIdx.x;
  const int t = tok[row];
  const float4* s = (const float4*)(embed + (size_t)t * DD);
  const float4 a = s[tid], b = s[tid + 256];
  float ss = a.x * a.x + a.y * a.y + a.z * a.z + a.w * a.w +
             b.x * b.x + b.y * b.y + b.z * b.z + b.w * b.w;
#pragma unroll
  for (int m = 32; m; m >>= 1) ss += __shfl_xor(ss, m);
  __shared__ float part[4];
  if ((tid & 63) == 0) part[tid >> 6] = ss;
  __syncthreads();
  if (tid == 0) p0[(size_t)row * 8] = part[0] + part[1] + part[2] + part[3];
  ushort4 o0, o1;
  o0.x = f2bf(a.x); o0.y = f2bf(a.y); o0.z = f2bf(a.z); o0.w = f2bf(a.w);
  o1.x = f2bf(b.x); o1.y = f2bf(b.y); o1.z = f2bf(b.z); o1.w = f2bf(b.w);
  ushort4* d = (ushort4*)(h0 + (size_t)row * DD);
  d[tid] = o0;
  d[tid + 256] = o1;
}

// ---------------- W reconstruction via MFMA, norm_w folded (r11) ----------------
__global__ __launch_bounds__(256) void k_wrec(
    const float* __restrict__ hr, const float* __restrict__ hi,
    const float* __restrict__ kar, const float* __restrict__ kai,
    const float* __restrict__ kbr, const float* __restrict__ kbi,
    const float* __restrict__ scale, const float* __restrict__ nw,
    unsigned short* __restrict__ W) {
  __shared__ float KAR[16][132], KAI[16][132];
  __shared__ float KBR[16][68], KBI[16][68];
  __shared__ unsigned short Wt[128][72];
  const int tid = threadIdx.x;
  const int lane = tid & 63, w = tid >> 6;
  const int fr = lane & 15, g = lane >> 4;
  const int o0 = blockIdx.x * 128, i0 = blockIdx.y * 64;

  float hrg[2][4][4], hig[2][4][4];
#pragma unroll
  for (int of = 0; of < 2; ++of)
#pragma unroll
    for (int jj = 0; jj < 4; ++jj) {
      const size_t orow = (size_t)(o0 + w * 32 + of * 16 + g * 4 + jj) * DD + i0;
#pragma unroll
      for (int fi = 0; fi < 4; ++fi) {
        hrg[of][jj][fi] = hr[orow + fi * 16 + fr];
        hig[of][jj][fi] = hi[orow + fi * 16 + fr];
      }
    }

  const int sr = tid >> 4;
  const int sca = (tid & 15) * 8;
  const int scb = (tid & 15) * 4;
  const int rlo = (g & 1) * 8;

  for (int f = 0; f < NF; ++f) {
    __syncthreads();
    {
      const size_t ga = ((size_t)f * 16 + sr) * DD;
      *(float4*)&KAR[sr][sca]     = *(const float4*)&kar[ga + o0 + sca];
      *(float4*)&KAR[sr][sca + 4] = *(const float4*)&kar[ga + o0 + sca + 4];
      *(float4*)&KAI[sr][sca]     = *(const float4*)&kai[ga + o0 + sca];
      *(float4*)&KAI[sr][sca + 4] = *(const float4*)&kai[ga + o0 + sca + 4];
      *(float4*)&KBR[sr][scb]     = *(const float4*)&kbr[ga + i0 + scb];
      *(float4*)&KBI[sr][scb]     = *(const float4*)&kbi[ga + i0 + scb];
    }
    __syncthreads();
    bf16x8 aPr[2], aPi[2], bF[4];
#pragma unroll
    for (int of = 0; of < 2; ++of) {
      const int oc = w * 32 + of * 16 + fr;
      union { bf16x8 v; unsigned short u[8]; } pu, pv;
#pragma unroll
      for (int j = 0; j < 8; ++j) {
        const float ka = KAR[rlo + j][oc];
        const float kb = KAI[rlo + j][oc];
        pu.u[j] = f2bf((g < 2) ? ka : kb);
        pv.u[j] = f2bf((g < 2) ? kb : -ka);
      }
      aPr[of] = pu.v; aPi[of] = pv.v;
    }
#pragma unroll
    for (int fi = 0; fi < 4; ++fi) {
      const int ic = fi * 16 + fr;
      union { bf16x8 v; unsigned short u[8]; } pb;
#pragma unroll
      for (int j = 0; j < 8; ++j) {
        const float vr = KBR[rlo + j][ic];
        const float vi = KBI[rlo + j][ic];
        pb.u[j] = f2bf((g < 2) ? vr : vi);
      }
      bF[fi] = pb.v;
    }
    const float sc = scale[f];
    float nwv[4];
#pragma unroll
    for (int fi = 0; fi < 4; ++fi) nwv[fi] = nw[(size_t)f * DD + i0 + fi * 16 + fr];
#pragma unroll
    for (int of = 0; of < 2; ++of)
#pragma unroll
      for (int fi = 0; fi < 4; ++fi) {
        const f32x4 z = (f32x4){0.f, 0.f, 0.f, 0.f};
        const f32x4 cr = __builtin_amdgcn_mfma_f32_16x16x32_bf16(aPr[of], bF[fi], z, 0, 0, 0);
        const f32x4 ci = __builtin_amdgcn_mfma_f32_16x16x32_bf16(aPi[of], bF[fi], z, 0, 0, 0);
#pragma unroll
        for (int jj = 0; jj < 4; ++jj) {
          const float wv = (hrg[of][jj][fi] * cr[jj] - hig[of][jj][fi] * ci[jj]) * sc * nwv[fi];
          Wt[w * 32 + of * 16 + g * 4 + jj][fi * 16 + fr] = f2bf(wv);
        }
      }
    __syncthreads();
    {
      const int r = tid >> 1, hh = tid & 1;
      unsigned short* dst = W + ((size_t)f * DD + o0 + r) * DD + i0 + hh * 32;
#pragma unroll
      for (int qq = 0; qq < 4; ++qq)
        *(uint4*)(dst + qq * 8) = *(const uint4*)&Wt[r][hh * 32 + qq * 8];
    }
  }
}

// ---------------- layer GEMM: ring-3 (r8 schedule) + fused norm (r11) ----------------
template <int ACT>
__global__ __launch_bounds__(512, 2) void k_gemmL(const unsigned short* __restrict__ Hin,
                                                  const unsigned short* __restrict__ B,
                                                  unsigned short* __restrict__ Hout,
                                                  const float* __restrict__ Pin,
                                                  float* __restrict__ Pout) {
  constexpr int NTILE = DD / 64;  // 32
  __shared__ unsigned short lsA[3][8192];    // [slot][128 rows][64 k]
  __shared__ unsigned short lsB[3][16384];   // [slot][256 rows][64 k]
  __shared__ float invS[128];
  __shared__ float rsum[128];
  const int tid = threadIdx.x;
  const int lane = tid & 63, wave = tid >> 6;
  const int wm = wave >> 2, wn = wave & 3;
  const int bid = blockIdx.x;
  const int swz = (bid & 7) * 32 + (bid >> 3);   // 256 blocks: XCD-contig
  const int t0 = (swz & 31) * 128;
  const int n0 = (swz >> 5) * 256;
  const unsigned short* Ab = Hin + (size_t)t0 * DD;
  const unsigned short* Bb = B + (size_t)n0 * DD;
  const int fr = lane & 15, g = lane >> 4;
  const int srow8 = tid >> 3, sslot = tid & 7;

#define LSTG_A(slot, tile)                                                          \
  { _Pragma("unroll")                                                               \
    for (int l = 0; l < 2; ++l) {                                                   \
      const int rt = l * 64 + srow8;                                                \
      gload_lds16(Ab + (size_t)rt * DD + (tile) * 64 + ((sslot ^ (rt & 7)) << 3),   \
                  &lsA[slot][rt * 64 + sslot * 8]);                                 \
    } }
#define LSTG_B(slot, h, tile)                                                       \
  { _Pragma("unroll")                                                               \
    for (int l = 0; l < 2; ++l) {                                                   \
      const int rt = (h) * 128 + l * 64 + srow8;                                    \
      gload_lds16(Bb + (size_t)rt * DD + (tile) * 64 + ((sslot ^ (rt & 7)) << 3),   \
                  &lsB[slot][rt * 64 + sslot * 8]);                                 \
    } }
#define LRD_A(slot, mi, ks)                                                         \
  (*(const bf16x8*)&lsA[slot][(wm * 64 + (mi) * 16 + fr) * 64 +                     \
                              ((((ks) * 4 + g) ^ ((wm * 64 + (mi) * 16 + fr) & 7)) << 3)])
#define LRD_B(slot, ni, ks)                                                         \
  (*(const bf16x8*)&lsB[slot][(wn * 64 + (ni) * 16 + fr) * 64 +                     \
                              ((((ks) * 4 + g) ^ ((wn * 64 + (ni) * 16 + fr) & 7)) << 3)])

  f32x4 acc[4][4];
#pragma unroll
  for (int i = 0; i < 4; ++i)
#pragma unroll
    for (int j = 0; j < 4; ++j) acc[i][j] = (f32x4){0.f, 0.f, 0.f, 0.f};

  bf16x8 aF[4][2], bF[2][2];

#define LTILE(t, sc, sp)                                                            \
  {                                                                                 \
    const bool st = (t) + 2 < NTILE;                                                \
    /* ---- phase nh0 ---- */                                                       \
    _Pragma("unroll")                                                               \
    for (int mi = 0; mi < 4; ++mi) { _Pragma("unroll")                              \
      for (int ks = 0; ks < 2; ++ks) aF[mi][ks] = LRD_A(sc, mi, ks); }              \
    _Pragma("unroll")                                                               \
    for (int q = 0; q < 2; ++q) { _Pragma("unroll")                                 \
      for (int ks = 0; ks < 2; ++ks) bF[q][ks] = LRD_B(sc, q, ks); }                \
    if (st) { LSTG_A(sp, (t) + 2); LSTG_B(sp, 0, (t) + 2); }                        \
    __builtin_amdgcn_s_barrier();                                                   \
    asm volatile("s_waitcnt lgkmcnt(0)" ::: "memory");                              \
    __builtin_amdgcn_s_setprio(1);                                                  \
    _Pragma("unroll")                                                               \
    for (int ks = 0; ks < 2; ++ks) { _Pragma("unroll")                              \
      for (int mi = 0; mi < 4; ++mi) { _Pragma("unroll")                            \
        for (int q = 0; q < 2; ++q)                                                 \
          acc[mi][q] = __builtin_amdgcn_mfma_f32_16x16x32_bf16(                     \
              aF[mi][ks], bF[q][ks], acc[mi][q], 0, 0, 0); } }                      \
    __builtin_amdgcn_s_setprio(0);                                                  \
    __builtin_amdgcn_s_barrier();                                                   \
    /* ---- phase nh1 ---- */                                                       \
    _Pragma("unroll")                                                               \
    for (int q = 0; q < 2; ++q) { _Pragma("unroll")                                 \
      for (int ks = 0; ks < 2; ++ks) bF[q][ks] = LRD_B(sc, 2 + q, ks); }            \
    if (st) LSTG_B(sp, 1, (t) + 2);                                                 \
    if (st) asm volatile("s_waitcnt vmcnt(6)" ::: "memory");                        \
    else    asm volatile("s_waitcnt vmcnt(0)" ::: "memory");                        \
    __builtin_amdgcn_s_barrier();                                                   \
    asm volatile("s_waitcnt lgkmcnt(0)" ::: "memory");                              \
    __builtin_amdgcn_s_setprio(1);                                                  \
    _Pragma("unroll")                                                               \
    for (int ks = 0; ks < 2; ++ks) { _Pragma("unroll")                              \
      for (int mi = 0; mi < 4; ++mi) { _Pragma("unroll")                            \
        for (int q = 0; q < 2; ++q)                                                 \
          acc[mi][2 + q] = __builtin_amdgcn_mfma_f32_16x16x32_bf16(                 \
              aF[mi][ks], bF[q][ks], acc[mi][2 + q], 0, 0, 0); } }                  \
    __builtin_amdgcn_s_setprio(0);                                                  \
    __builtin_amdgcn_s_barrier();                                                   \
  }

  LSTG_A(0, 0); LSTG_B(0, 0, 0); LSTG_B(0, 1, 0);
  LSTG_A(1, 1); LSTG_B(1, 0, 1); LSTG_B(1, 1, 1);
  // fused-norm prologue: inv per row from 8 panel partials
  if (tid < 128) {
    const float* pr = Pin + (size_t)(t0 + tid) * 8;
    const float s = pr[0] + pr[1] + pr[2] + pr[3] + pr[4] + pr[5] + pr[6] + pr[7];
    invS[tid] = rsqrtf(s * (1.f / DD) + EPS_F);
  }
  asm volatile("s_waitcnt vmcnt(6)" ::: "memory");
  __builtin_amdgcn_s_barrier();

  for (int tb = 0; tb < 30; tb += 3) {
    LTILE(tb, 0, 2);
    LTILE(tb + 1, 1, 0);
    LTILE(tb + 2, 2, 1);
  }
  LTILE(30, 0, 2);
  LTILE(31, 1, 0);
#undef LTILE
#undef LRD_A
#undef LRD_B
#undef LSTG_A
#undef LSTG_B

  // epilogue: apply inv, residual-add into Hout, per-row sumsq partial -> Pout
  __syncthreads();
  if (tid < 128) rsum[tid] = 0.f;
  __syncthreads();
  const int panel = n0 >> 8;
#pragma unroll
  for (int mi = 0; mi < 4; ++mi) {
#pragma unroll
    for (int j = 0; j < 4; ++j) {
      const int lr = wm * 64 + mi * 16 + g * 4 + j;
      const float iv = invS[lr];
      float racc = 0.f;
#pragma unroll
      for (int ni = 0; ni < 4; ++ni) {
        const size_t idx = (size_t)(t0 + lr) * DD + (n0 + wn * 64 + ni * 16 + fr);
        const float v = acc[mi][ni][j] * iv;
        const float old = bf2f(Hin[idx]);
        float nv;
        if (ACT == 0) nv = old + v;
        else          nv = old + v / (1.f + __expf(-v));
        Hout[idx] = f2bf(nv);
        racc += nv * nv;
      }
      racc += __shfl_xor(racc, 1);
      racc += __shfl_xor(racc, 2);
      racc += __shfl_xor(racc, 4);
      racc += __shfl_xor(racc, 8);
      if (fr == 0) atomicAdd(&rsum[lr], racc);
    }
  }
  __syncthreads();
  if (tid < 128) Pout[(size_t)(t0 + tid) * 8 + panel] = rsum[tid];
}

// ---------------- 8-phase GEMM for LM head (r7 schedule + inv scale) ----------------
// C[t][n] = inv[t] * sum_k A[t][k]*B[n][k].
// Tile mapping m-slow/n-fast: each XCD's contiguous swz range covers exactly
// 2 A-slabs (2MB, L2-resident) x 125 n-panels; all XCDs sweep B panels in
// near-lockstep -> each B panel fetched from HBM ~once into L3, hit 8x.
// (Old m-fast mapping thrashed 16MB of A through L2/L3 under the 512MB
// C-write stream: FETCH 750MB vs ~150 ideal.)
template <int BM>
__global__ __launch_bounds__(512, 2) void k_gemm8(const unsigned short* __restrict__ A,
                                                  const unsigned short* __restrict__ B,
                                                  float* __restrict__ C, const int ldc,
                                                  const int npan,
                                                  const float* __restrict__ Pin) {
  constexpr int HALF = BM / 2;
  constexpr int MI = BM / 32;
  constexpr int MQ = MI / 2;
  constexpr int A_LOADS = HALF / 64;
  constexpr int NTILE = DD / 64;
  constexpr int NITER = NTILE / 2;

  __shared__ unsigned short lsA[2][BM * 64];
  __shared__ unsigned short lsB[2][256 * 64];
  __shared__ float invS[BM];

  const int tid = threadIdx.x;
  const int lane = tid & 63, wave = tid >> 6;
  const int wm = wave >> 2, wn = wave & 3;
  const int bid = blockIdx.x;
  const int swz = (bid & 7) * (gridDim.x >> 3) + (bid >> 3);
  const int t0 = (swz / npan) * BM;   // m slow within XCD
  const int n0 = (swz % npan) * 256;  // n fast within XCD
  const unsigned short* Ab = A + (size_t)t0 * DD;
  const unsigned short* Bb = B + (size_t)n0 * DD;
  const int fr = lane & 15, g = lane >> 4;
  const int srow8 = tid >> 3, sslot = tid & 7;

#define STG_A(buf, h, tile)                                                         \
  { _Pragma("unroll")                                                               \
    for (int l = 0; l < A_LOADS; ++l) {                                             \
      const int rt = (h) * HALF + l * 64 + srow8;                                   \
      gload_lds16(Ab + (size_t)rt * DD + (tile) * 64 + ((sslot ^ (rt & 7)) << 3),   \
                  &lsA[buf][rt * 64 + sslot * 8]);                                  \
    } }
#define STG_B(buf, h, tile)                                                         \
  { _Pragma("unroll")                                                               \
    for (int l = 0; l < 2; ++l) {                                                   \
      const int rt = (h) * 128 + l * 64 + srow8;                                    \
      gload_lds16(Bb + (size_t)rt * DD + (tile) * 64 + ((sslot ^ (rt & 7)) << 3),   \
                  &lsB[buf][rt * 64 + sslot * 8]);                                  \
    } }
#define VM_G3()                                                                     \
  { if constexpr (BM == 256) asm volatile("s_waitcnt vmcnt(6)" ::: "memory");       \
    else                     asm volatile("s_waitcnt vmcnt(5)" ::: "memory"); }
#define VM_G7()                                                                     \
  { if constexpr (BM == 256) asm volatile("s_waitcnt vmcnt(8)" ::: "memory");       \
    else                     asm volatile("s_waitcnt vmcnt(6)" ::: "memory"); }
#define VM_PRO()                                                                    \
  { if constexpr (BM == 256) asm volatile("s_waitcnt vmcnt(8)" ::: "memory");       \
    else                     asm volatile("s_waitcnt vmcnt(6)" ::: "memory"); }
#define VM_ZERO() asm volatile("s_waitcnt vmcnt(0)" ::: "memory")

  f32x4 acc[MI][4];
#pragma unroll
  for (int i = 0; i < MI; ++i)
#pragma unroll
    for (int j = 0; j < 4; ++j) acc[i][j] = (f32x4){0.f, 0.f, 0.f, 0.f};

  bf16x8 aF[MQ][2];
  bf16x8 bF[2][2][2];

#define RD_A(buf, mi, ks)                                                           \
  (*(const bf16x8*)&lsA[buf][(wm * HALF + (mi) * 16 + fr) * 64 +                    \
                             ((((ks) * 4 + g) ^ ((wm * HALF + (mi) * 16 + fr) & 7)) << 3)])
#define RD_B(buf, ni, ks)                                                           \
  (*(const bf16x8*)&lsB[buf][(wn * 64 + (ni) * 16 + fr) * 64 +                      \
                             ((((ks) * 4 + g) ^ ((wn * 64 + (ni) * 16 + fr) & 7)) << 3)])

#define PHASE(buf, mh, nh, LA, LB, STAGES, VMK)                                     \
  {                                                                                 \
    if (LA) { _Pragma("unroll")                                                     \
      for (int q = 0; q < MQ; ++q) { _Pragma("unroll")                              \
        for (int ks = 0; ks < 2; ++ks) aF[q][ks] = RD_A(buf, (mh) * MQ + q, ks); } }\
    if (LB) { _Pragma("unroll")                                                     \
      for (int q = 0; q < 2; ++q) { _Pragma("unroll")                               \
        for (int ks = 0; ks < 2; ++ks) bF[nh][q][ks] = RD_B(buf, (nh) * 2 + q, ks); } } \
    STAGES;                                                                         \
    VMK;                                                                            \
    __builtin_amdgcn_s_barrier();                                                   \
    asm volatile("s_waitcnt lgkmcnt(0)" ::: "memory");                              \
    __builtin_amdgcn_s_setprio(1);                                                  \
    _Pragma("unroll")                                                               \
    for (int ks = 0; ks < 2; ++ks) { _Pragma("unroll")                              \
      for (int q = 0; q < MQ; ++q) { _Pragma("unroll")                              \
        for (int nq = 0; nq < 2; ++nq)                                              \
          acc[(mh) * MQ + q][(nh) * 2 + nq] = __builtin_amdgcn_mfma_f32_16x16x32_bf16( \
              aF[q][ks], bF[nh][nq][ks], acc[(mh) * MQ + q][(nh) * 2 + nq], 0, 0, 0); } } \
    __builtin_amdgcn_s_setprio(0);                                                  \
    __builtin_amdgcn_s_barrier();                                                   \
  }

  STG_B(0, 0, 0); STG_B(0, 1, 0); STG_A(0, 0, 0); STG_A(0, 1, 0);
  STG_B(1, 0, 1); STG_B(1, 1, 1); STG_A(1, 0, 1); STG_A(1, 1, 1);
  if (tid < BM) {
    const float* pr = Pin + (size_t)(t0 + tid) * 8;
    const float s = pr[0] + pr[1] + pr[2] + pr[3] + pr[4] + pr[5] + pr[6] + pr[7];
    invS[tid] = rsqrtf(s * (1.f / DD) + EPS_F);
  }
  VM_PRO();
  __builtin_amdgcn_s_barrier();

  for (int i = 0; i < NITER; ++i) {
    const int T2 = 2 * i + 2, T3 = 2 * i + 3;
    const bool s2 = T2 < NTILE, s3 = T3 < NTILE;
    PHASE(0, 0, 0, true,  true,  {}, {});
    PHASE(0, 0, 1, false, true,  {}, {});
    PHASE(0, 1, 1, true,  false, { if (s2) { STG_B(0, 0, T2); STG_B(0, 1, T2); } }, {});
    PHASE(0, 1, 0, false, false, { if (s2) STG_A(0, 0, T2); },
          { if (s2) VM_G3() else VM_ZERO(); });
    PHASE(1, 0, 0, true,  true,  { if (s2) STG_A(0, 1, T2); }, {});
    PHASE(1, 0, 1, false, true,  {}, {});
    PHASE(1, 1, 1, true,  false, { if (s3) { STG_B(1, 0, T3); STG_B(1, 1, T3); } }, {});
    PHASE(1, 1, 0, false, false, { if (s3) { STG_A(1, 0, T3); STG_A(1, 1, T3); } },
          { if (s3) VM_G7() else VM_ZERO(); });
  }
#undef PHASE
#undef RD_A
#undef RD_B
#undef STG_A
#undef STG_B
#undef VM_G3
#undef VM_G7
#undef VM_PRO
#undef VM_ZERO

#pragma unroll
  for (int mi = 0; mi < MI; ++mi) {
#pragma unroll
    for (int ni = 0; ni < 4; ++ni) {
      const int ocol = n0 + wn * 64 + ni * 16 + fr;
#pragma unroll
      for (int j = 0; j < 4; ++j) {
        const int lr = wm * HALF + mi * 16 + g * 4 + j;
        const size_t idx = (size_t)(t0 + lr) * ldc + ocol;
        C[idx] = invS[lr] * acc[mi][ni][j];
      }
    }
  }
}

// ---------------- lm_bf16 = bf16(lm * fnw) ----------------
__global__ void k_cvt(const float* __restrict__ in, const float* __restrict__ fnw,
                      unsigned short* __restrict__ out, int n4) {
  int i = blockIdx.x * blockDim.x + threadIdx.x;
  const int stride = gridDim.x * blockDim.x;
  for (; i < n4; i += stride) {
    const float4 v = ((const float4*)in)[i];
    const float4 w = ((const float4*)fnw)[i & 511];  // DD/4 = 512
    ushort4 o;
    o.x = f2bf(v.x * w.x); o.y = f2bf(v.y * w.y);
    o.z = f2bf(v.z * w.z); o.w = f2bf(v.w * w.w);
    ((ushort4*)out)[i] = o;
  }
}

extern "C" void kernel_launch(void* const* d_in, const int* in_sizes, int n_in,
                              void* d_out, int out_size, void* d_ws, size_t ws_size,
                              hipStream_t stream) {
  (void)in_sizes; (void)n_in; (void)out_size; (void)ws_size;
  const int* tokens = (const int*)d_in[0];
  const float* hr = (const float*)d_in[1];
  const float* hi = (const float*)d_in[2];
  const float* kar = (const float*)d_in[3];
  const float* kai = (const float*)d_in[4];
  const float* kbr = (const float*)d_in[5];
  const float* kbi = (const float*)d_in[6];
  const float* lscale = (const float*)d_in[7];
  const float* norm_w = (const float*)d_in[8];
  const float* embed = (const float*)d_in[9];
  const float* lm = (const float*)d_in[10];
  const float* fnw = (const float*)d_in[11];
  float* out = (float*)d_out;
  char* ws = (char*)d_ws;

  // ws: W' 192MB | P0,P1 (4096x8 f32 each) | hA bf16 16.7MB.
  // hB = first 16.7MB of d_out (dead before LM writes d_out; parity: 24 swaps).
  // lmb overlays W' (dead after last layer). Norm fused: W' carries norm_w,
  // lmb carries fnw, 1/rms applied in GEMM epilogues via P ping-pong.
  unsigned short* W = (unsigned short*)ws;
  float* P0 = (float*)(ws + 201326592);
  float* P1 = P0 + (size_t)NROWS * 8;
  unsigned short* hA = (unsigned short*)(ws + 201326592 + 262144);
  unsigned short* hB = (unsigned short*)d_out;
  unsigned short* lmb = W;

  hipMemsetAsync(P0, 0, (size_t)NROWS * 8 * sizeof(float), stream);
  k_gather<<<NROWS, 256, 0, stream>>>(tokens, embed, hA, P0);
  k_wrec<<<dim3(16, 32), 256, 0, stream>>>(hr, hi, kar, kai, kbr, kbi, lscale,
                                           norm_w, W);
  const unsigned short* cin = hA;
  unsigned short* cout = hB;
  const float* pin = P0;
  float* pout = P1;
  for (int l = 0; l < 12; ++l) {
    k_gemmL<0><<<256, 512, 0, stream>>>(cin, W + (size_t)(2 * l) * DD * DD, cout, pin, pout);
    { const unsigned short* tc = cin; cin = cout; cout = (unsigned short*)tc;
      const float* tp = pin; pin = pout; pout = (float*)tp; }
    k_gemmL<1><<<256, 512, 0, stream>>>(cin, W + (size_t)(2 * l + 1) * DD * DD, cout, pin, pout);
    { const unsigned short* tc = cin; cin = cout; cout = (unsigned short*)tc;
      const float* tp = pin; pin = pout; pout = (float*)tp; }
  }
  // after 24 swaps: cin == hA, pin == P0
  k_cvt<<<2048, 256, 0, stream>>>(lm, fnw, lmb, VOCAB_N * DD / 4);
  k_gemm8<256><<<2000, 512, 0, stream>>>(cin, lmb, out, VOCAB_N, 125, pin);
}

// Round 15
// 1901.816 us; speedup vs baseline: 1.2694x; 1.0064x over previous
//
#include <hip/hip_runtime.h>
#include <hip/hip_bf16.h>

#define DD 2048
#define NF 24
#define NROWS 4096
#define VOCAB_N 32000
#define EPS_F 1.1920929e-07f

typedef __attribute__((ext_vector_type(8))) __bf16 bf16x8;
typedef __attribute__((ext_vector_type(4))) float f32x4;

__device__ __forceinline__ unsigned short f2bf(float f) {
  union { float f; unsigned int u; } v; v.f = f;
  unsigned int r = v.u + 0x7fffu + ((v.u >> 16) & 1u);  // RNE
  return (unsigned short)(r >> 16);
}
__device__ __forceinline__ float bf2f(unsigned short u) {
  union { unsigned int i; float f; } v; v.i = ((unsigned int)u) << 16; return v.f;
}

__device__ __forceinline__ void gload_lds16(const void* g, void* l) {
  __builtin_amdgcn_global_load_lds(
      (const __attribute__((address_space(1))) void*)g,
      (__attribute__((address_space(3))) void*)l, 16, 0, 0);
}

// ---------------- gather: h0 = bf16(embed[tok]); P0[row][0] = sumsq ----------------
__global__ __launch_bounds__(256) void k_gather(const int* __restrict__ tok,
                                                const float* __restrict__ embed,
                                                unsigned short* __restrict__ h0,
                                                float* __restrict__ p0) {
  const int row = blockIdx.x, tid = threadIdx.x;
  const int t = tok[row];
  const float4* s = (const float4*)(embed + (size_t)t * DD);
  const float4 a = s[tid], b = s[tid + 256];
  float ss = a.x * a.x + a.y * a.y + a.z * a.z + a.w * a.w +
             b.x * b.x + b.y * b.y + b.z * b.z + b.w * b.w;
#pragma unroll
  for (int m = 32; m; m >>= 1) ss += __shfl_xor(ss, m);
  __shared__ float part[4];
  if ((tid & 63) == 0) part[tid >> 6] = ss;
  __syncthreads();
  if (tid == 0) p0[(size_t)row * 8] = part[0] + part[1] + part[2] + part[3];
  ushort4 o0, o1;
  o0.x = f2bf(a.x); o0.y = f2bf(a.y); o0.z = f2bf(a.z); o0.w = f2bf(a.w);
  o1.x = f2bf(b.x); o1.y = f2bf(b.y); o1.z = f2bf(b.z); o1.w = f2bf(b.w);
  ushort4* d = (ushort4*)(h0 + (size_t)row * DD);
  d[tid] = o0;
  d[tid + 256] = o1;
}

// ---------------- W reconstruction via MFMA, norm_w folded (r11) ----------------
__global__ __launch_bounds__(256) void k_wrec(
    const float* __restrict__ hr, const float* __restrict__ hi,
    const float* __restrict__ kar, const float* __restrict__ kai,
    const float* __restrict__ kbr, const float* __restrict__ kbi,
    const float* __restrict__ scale, const float* __restrict__ nw,
    unsigned short* __restrict__ W) {
  __shared__ float KAR[16][132], KAI[16][132];
  __shared__ float KBR[16][68], KBI[16][68];
  __shared__ unsigned short Wt[128][72];
  const int tid = threadIdx.x;
  const int lane = tid & 63, w = tid >> 6;
  const int fr = lane & 15, g = lane >> 4;
  const int o0 = blockIdx.x * 128, i0 = blockIdx.y * 64;

  float hrg[2][4][4], hig[2][4][4];
#pragma unroll
  for (int of = 0; of < 2; ++of)
#pragma unroll
    for (int jj = 0; jj < 4; ++jj) {
      const size_t orow = (size_t)(o0 + w * 32 + of * 16 + g * 4 + jj) * DD + i0;
#pragma unroll
      for (int fi = 0; fi < 4; ++fi) {
        hrg[of][jj][fi] = hr[orow + fi * 16 + fr];
        hig[of][jj][fi] = hi[orow + fi * 16 + fr];
      }
    }

  const int sr = tid >> 4;
  const int sca = (tid & 15) * 8;
  const int scb = (tid & 15) * 4;
  const int rlo = (g & 1) * 8;

  for (int f = 0; f < NF; ++f) {
    __syncthreads();
    {
      const size_t ga = ((size_t)f * 16 + sr) * DD;
      *(float4*)&KAR[sr][sca]     = *(const float4*)&kar[ga + o0 + sca];
      *(float4*)&KAR[sr][sca + 4] = *(const float4*)&kar[ga + o0 + sca + 4];
      *(float4*)&KAI[sr][sca]     = *(const float4*)&kai[ga + o0 + sca];
      *(float4*)&KAI[sr][sca + 4] = *(const float4*)&kai[ga + o0 + sca + 4];
      *(float4*)&KBR[sr][scb]     = *(const float4*)&kbr[ga + i0 + scb];
      *(float4*)&KBI[sr][scb]     = *(const float4*)&kbi[ga + i0 + scb];
    }
    __syncthreads();
    bf16x8 aPr[2], aPi[2], bF[4];
#pragma unroll
    for (int of = 0; of < 2; ++of) {
      const int oc = w * 32 + of * 16 + fr;
      union { bf16x8 v; unsigned short u[8]; } pu, pv;
#pragma unroll
      for (int j = 0; j < 8; ++j) {
        const float ka = KAR[rlo + j][oc];
        const float kb = KAI[rlo + j][oc];
        pu.u[j] = f2bf((g < 2) ? ka : kb);
        pv.u[j] = f2bf((g < 2) ? kb : -ka);
      }
      aPr[of] = pu.v; aPi[of] = pv.v;
    }
#pragma unroll
    for (int fi = 0; fi < 4; ++fi) {
      const int ic = fi * 16 + fr;
      union { bf16x8 v; unsigned short u[8]; } pb;
#pragma unroll
      for (int j = 0; j < 8; ++j) {
        const float vr = KBR[rlo + j][ic];
        const float vi = KBI[rlo + j][ic];
        pb.u[j] = f2bf((g < 2) ? vr : vi);
      }
      bF[fi] = pb.v;
    }
    const float sc = scale[f];
    float nwv[4];
#pragma unroll
    for (int fi = 0; fi < 4; ++fi) nwv[fi] = nw[(size_t)f * DD + i0 + fi * 16 + fr];
#pragma unroll
    for (int of = 0; of < 2; ++of)
#pragma unroll
      for (int fi = 0; fi < 4; ++fi) {
        const f32x4 z = (f32x4){0.f, 0.f, 0.f, 0.f};
        const f32x4 cr = __builtin_amdgcn_mfma_f32_16x16x32_bf16(aPr[of], bF[fi], z, 0, 0, 0);
        const f32x4 ci = __builtin_amdgcn_mfma_f32_16x16x32_bf16(aPi[of], bF[fi], z, 0, 0, 0);
#pragma unroll
        for (int jj = 0; jj < 4; ++jj) {
          const float wv = (hrg[of][jj][fi] * cr[jj] - hig[of][jj][fi] * ci[jj]) * sc * nwv[fi];
          Wt[w * 32 + of * 16 + g * 4 + jj][fi * 16 + fr] = f2bf(wv);
        }
      }
    __syncthreads();
    {
      const int r = tid >> 1, hh = tid & 1;
      unsigned short* dst = W + ((size_t)f * DD + o0 + r) * DD + i0 + hh * 32;
#pragma unroll
      for (int qq = 0; qq < 4; ++qq)
        *(uint4*)(dst + qq * 8) = *(const uint4*)&Wt[r][hh * 32 + qq * 8];
    }
  }
}

// ---------------- layer GEMM: ring-3, ONE barrier-pair per K-tile, 32 MFMA ----------------
// Hout[t][n] = bf16( Hin[t][n] + act( inv[t] * sum_k Hin[t][k]*W'[n][k] ) )
// Merged phase per K-tile t (slot sc=t%3, stage slot sp=(t+2)%3=(t-1)%3):
//  { ds_read ALL frags (A 8 + B 8 b128) | stage tile t+2 (6 gloads) | vmcnt(6)
//    [tail: 0] | BAR | lgkm0 | setprio1 32 MFMA setprio0 | BAR }
// vs r8's 2 pairs/K-tile: halves barrier-rendezvous overhead (~240 cyc/pair).
// Gate ledger: in flight at gate = t+1's 6 + t+2's 6; vmcnt(6) retires t+1
// (consumed next phase; barrier => cross-wave visibility). Write safety: slot
// sp=(t-1)%3 — tile t-1's reads retired by each wave's lgkm0 before its MFMA,
// which precedes BAR2(t-1), which precedes every wave's stage at phase t.
// Swizzle: k-slot s at row r holds global slot s^(r&7) (pre-swizzled source).
template <int ACT>
__global__ __launch_bounds__(512, 2) void k_gemmL(const unsigned short* __restrict__ Hin,
                                                  const unsigned short* __restrict__ B,
                                                  unsigned short* __restrict__ Hout,
                                                  const float* __restrict__ Pin,
                                                  float* __restrict__ Pout) {
  constexpr int NTILE = DD / 64;  // 32
  __shared__ unsigned short lsA[3][8192];    // [slot][128 rows][64 k]
  __shared__ unsigned short lsB[3][16384];   // [slot][256 rows][64 k]
  __shared__ float invS[128];
  __shared__ float rsum[128];
  const int tid = threadIdx.x;
  const int lane = tid & 63, wave = tid >> 6;
  const int wm = wave >> 2, wn = wave & 3;
  const int bid = blockIdx.x;
  const int swz = (bid & 7) * 32 + (bid >> 3);   // 256 blocks: XCD-contig
  const int t0 = (swz & 31) * 128;
  const int n0 = (swz >> 5) * 256;
  const unsigned short* Ab = Hin + (size_t)t0 * DD;
  const unsigned short* Bb = B + (size_t)n0 * DD;
  const int fr = lane & 15, g = lane >> 4;
  const int srow8 = tid >> 3, sslot = tid & 7;

#define LSTG_A(slot, tile)                                                          \
  { _Pragma("unroll")                                                               \
    for (int l = 0; l < 2; ++l) {                                                   \
      const int rt = l * 64 + srow8;                                                \
      gload_lds16(Ab + (size_t)rt * DD + (tile) * 64 + ((sslot ^ (rt & 7)) << 3),   \
                  &lsA[slot][rt * 64 + sslot * 8]);                                 \
    } }
#define LSTG_B(slot, h, tile)                                                       \
  { _Pragma("unroll")                                                               \
    for (int l = 0; l < 2; ++l) {                                                   \
      const int rt = (h) * 128 + l * 64 + srow8;                                    \
      gload_lds16(Bb + (size_t)rt * DD + (tile) * 64 + ((sslot ^ (rt & 7)) << 3),   \
                  &lsB[slot][rt * 64 + sslot * 8]);                                 \
    } }
#define LRD_A(slot, mi, ks)                                                         \
  (*(const bf16x8*)&lsA[slot][(wm * 64 + (mi) * 16 + fr) * 64 +                     \
                              ((((ks) * 4 + g) ^ ((wm * 64 + (mi) * 16 + fr) & 7)) << 3)])
#define LRD_B(slot, ni, ks)                                                         \
  (*(const bf16x8*)&lsB[slot][(wn * 64 + (ni) * 16 + fr) * 64 +                     \
                              ((((ks) * 4 + g) ^ ((wn * 64 + (ni) * 16 + fr) & 7)) << 3)])

  f32x4 acc[4][4];
#pragma unroll
  for (int i = 0; i < 4; ++i)
#pragma unroll
    for (int j = 0; j < 4; ++j) acc[i][j] = (f32x4){0.f, 0.f, 0.f, 0.f};

  bf16x8 aF[4][2], bF[4][2];

#define LTILE(t, sc, sp)                                                            \
  {                                                                                 \
    const bool st = (t) + 2 < NTILE;                                                \
    _Pragma("unroll")                                                               \
    for (int mi = 0; mi < 4; ++mi) { _Pragma("unroll")                              \
      for (int ks = 0; ks < 2; ++ks) aF[mi][ks] = LRD_A(sc, mi, ks); }              \
    _Pragma("unroll")                                                               \
    for (int ni = 0; ni < 4; ++ni) { _Pragma("unroll")                              \
      for (int ks = 0; ks < 2; ++ks) bF[ni][ks] = LRD_B(sc, ni, ks); }              \
    if (st) { LSTG_A(sp, (t) + 2); LSTG_B(sp, 0, (t) + 2); LSTG_B(sp, 1, (t) + 2); }\
    if (st) asm volatile("s_waitcnt vmcnt(6)" ::: "memory");                        \
    else    asm volatile("s_waitcnt vmcnt(0)" ::: "memory");                        \
    __builtin_amdgcn_s_barrier();                                                   \
    asm volatile("s_waitcnt lgkmcnt(0)" ::: "memory");                              \
    __builtin_amdgcn_s_setprio(1);                                                  \
    _Pragma("unroll")                                                               \
    for (int ks = 0; ks < 2; ++ks) { _Pragma("unroll")                              \
      for (int mi = 0; mi < 4; ++mi) { _Pragma("unroll")                            \
        for (int ni = 0; ni < 4; ++ni)                                              \
          acc[mi][ni] = __builtin_amdgcn_mfma_f32_16x16x32_bf16(                    \
              aF[mi][ks], bF[ni][ks], acc[mi][ni], 0, 0, 0); } }                    \
    __builtin_amdgcn_s_setprio(0);                                                  \
    __builtin_amdgcn_s_barrier();                                                   \
  }

  LSTG_A(0, 0); LSTG_B(0, 0, 0); LSTG_B(0, 1, 0);
  LSTG_A(1, 1); LSTG_B(1, 0, 1); LSTG_B(1, 1, 1);
  // fused-norm prologue: inv per row from 8 panel partials
  if (tid < 128) {
    const float* pr = Pin + (size_t)(t0 + tid) * 8;
    const float s = pr[0] + pr[1] + pr[2] + pr[3] + pr[4] + pr[5] + pr[6] + pr[7];
    invS[tid] = rsqrtf(s * (1.f / DD) + EPS_F);
  }
  asm volatile("s_waitcnt vmcnt(6)" ::: "memory");
  __builtin_amdgcn_s_barrier();

  for (int tb = 0; tb < 30; tb += 3) {
    LTILE(tb, 0, 2);
    LTILE(tb + 1, 1, 0);
    LTILE(tb + 2, 2, 1);
  }
  LTILE(30, 0, 2);
  LTILE(31, 1, 0);
#undef LTILE
#undef LRD_A
#undef LRD_B
#undef LSTG_A
#undef LSTG_B

  // epilogue: apply inv, residual-add into Hout, per-row sumsq partial -> Pout
  __syncthreads();
  if (tid < 128) rsum[tid] = 0.f;
  __syncthreads();
  const int panel = n0 >> 8;
#pragma unroll
  for (int mi = 0; mi < 4; ++mi) {
#pragma unroll
    for (int j = 0; j < 4; ++j) {
      const int lr = wm * 64 + mi * 16 + g * 4 + j;
      const float iv = invS[lr];
      float racc = 0.f;
#pragma unroll
      for (int ni = 0; ni < 4; ++ni) {
        const size_t idx = (size_t)(t0 + lr) * DD + (n0 + wn * 64 + ni * 16 + fr);
        const float v = acc[mi][ni][j] * iv;
        const float old = bf2f(Hin[idx]);
        float nv;
        if (ACT == 0) nv = old + v;
        else          nv = old + v / (1.f + __expf(-v));
        Hout[idx] = f2bf(nv);
        racc += nv * nv;
      }
      racc += __shfl_xor(racc, 1);
      racc += __shfl_xor(racc, 2);
      racc += __shfl_xor(racc, 4);
      racc += __shfl_xor(racc, 8);
      if (fr == 0) atomicAdd(&rsum[lr], racc);
    }
  }
  __syncthreads();
  if (tid < 128) Pout[(size_t)(t0 + tid) * 8 + panel] = rsum[tid];
}

// ---------------- 8-phase GEMM for LM head (r14, frozen) ----------------
template <int BM>
__global__ __launch_bounds__(512, 2) void k_gemm8(const unsigned short* __restrict__ A,
                                                  const unsigned short* __restrict__ B,
                                                  float* __restrict__ C, const int ldc,
                                                  const int npan,
                                                  const float* __restrict__ Pin) {
  constexpr int HALF = BM / 2;
  constexpr int MI = BM / 32;
  constexpr int MQ = MI / 2;
  constexpr int A_LOADS = HALF / 64;
  constexpr int NTILE = DD / 64;
  constexpr int NITER = NTILE / 2;

  __shared__ unsigned short lsA[2][BM * 64];
  __shared__ unsigned short lsB[2][256 * 64];
  __shared__ float invS[BM];

  const int tid = threadIdx.x;
  const int lane = tid & 63, wave = tid >> 6;
  const int wm = wave >> 2, wn = wave & 3;
  const int bid = blockIdx.x;
  const int swz = (bid & 7) * (gridDim.x >> 3) + (bid >> 3);
  const int t0 = (swz / npan) * BM;   // m slow within XCD
  const int n0 = (swz % npan) * 256;  // n fast within XCD
  const unsigned short* Ab = A + (size_t)t0 * DD;
  const unsigned short* Bb = B + (size_t)n0 * DD;
  const int fr = lane & 15, g = lane >> 4;
  const int srow8 = tid >> 3, sslot = tid & 7;

#define STG_A(buf, h, tile)                                                         \
  { _Pragma("unroll")                                                               \
    for (int l = 0; l < A_LOADS; ++l) {                                             \
      const int rt = (h) * HALF + l * 64 + srow8;                                   \
      gload_lds16(Ab + (size_t)rt * DD + (tile) * 64 + ((sslot ^ (rt & 7)) << 3),   \
                  &lsA[buf][rt * 64 + sslot * 8]);                                  \
    } }
#define STG_B(buf, h, tile)                                                         \
  { _Pragma("unroll")                                                               \
    for (int l = 0; l < 2; ++l) {                                                   \
      const int rt = (h) * 128 + l * 64 + srow8;                                    \
      gload_lds16(Bb + (size_t)rt * DD + (tile) * 64 + ((sslot ^ (rt & 7)) << 3),   \
                  &lsB[buf][rt * 64 + sslot * 8]);                                  \
    } }
#define VM_G3()                                                                     \
  { if constexpr (BM == 256) asm volatile("s_waitcnt vmcnt(6)" ::: "memory");       \
    else                     asm volatile("s_waitcnt vmcnt(5)" ::: "memory"); }
#define VM_G7()                                                                     \
  { if constexpr (BM == 256) asm volatile("s_waitcnt vmcnt(8)" ::: "memory");       \
    else                     asm volatile("s_waitcnt vmcnt(6)" ::: "memory"); }
#define VM_PRO()                                                                    \
  { if constexpr (BM == 256) asm volatile("s_waitcnt vmcnt(8)" ::: "memory");       \
    else                     asm volatile("s_waitcnt vmcnt(6)" ::: "memory"); }
#define VM_ZERO() asm volatile("s_waitcnt vmcnt(0)" ::: "memory")

  f32x4 acc[MI][4];
#pragma unroll
  for (int i = 0; i < MI; ++i)
#pragma unroll
    for (int j = 0; j < 4; ++j) acc[i][j] = (f32x4){0.f, 0.f, 0.f, 0.f};

  bf16x8 aF[MQ][2];
  bf16x8 bF[2][2][2];

#define RD_A(buf, mi, ks)                                                           \
  (*(const bf16x8*)&lsA[buf][(wm * HALF + (mi) * 16 + fr) * 64 +                    \
                             ((((ks) * 4 + g) ^ ((wm * HALF + (mi) * 16 + fr) & 7)) << 3)])
#define RD_B(buf, ni, ks)                                                           \
  (*(const bf16x8*)&lsB[buf][(wn * 64 + (ni) * 16 + fr) * 64 +                      \
                             ((((ks) * 4 + g) ^ ((wn * 64 + (ni) * 16 + fr) & 7)) << 3)])

#define PHASE(buf, mh, nh, LA, LB, STAGES, VMK)                                     \
  {                                                                                 \
    if (LA) { _Pragma("unroll")                                                     \
      for (int q = 0; q < MQ; ++q) { _Pragma("unroll")                              \
        for (int ks = 0; ks < 2; ++ks) aF[q][ks] = RD_A(buf, (mh) * MQ + q, ks); } }\
    if (LB) { _Pragma("unroll")                                                     \
      for (int q = 0; q < 2; ++q) { _Pragma("unroll")                               \
        for (int ks = 0; ks < 2; ++ks) bF[nh][q][ks] = RD_B(buf, (nh) * 2 + q, ks); } } \
    STAGES;                                                                         \
    VMK;                                                                            \
    __builtin_amdgcn_s_barrier();                                                   \
    asm volatile("s_waitcnt lgkmcnt(0)" ::: "memory");                              \
    __builtin_amdgcn_s_setprio(1);                                                  \
    _Pragma("unroll")                                                               \
    for (int ks = 0; ks < 2; ++ks) { _Pragma("unroll")                              \
      for (int q = 0; q < MQ; ++q) { _Pragma("unroll")                              \
        for (int nq = 0; nq < 2; ++nq)                                              \
          acc[(mh) * MQ + q][(nh) * 2 + nq] = __builtin_amdgcn_mfma_f32_16x16x32_bf16( \
              aF[q][ks], bF[nh][nq][ks], acc[(mh) * MQ + q][(nh) * 2 + nq], 0, 0, 0); } } \
    __builtin_amdgcn_s_setprio(0);                                                  \
    __builtin_amdgcn_s_barrier();                                                   \
  }

  STG_B(0, 0, 0); STG_B(0, 1, 0); STG_A(0, 0, 0); STG_A(0, 1, 0);
  STG_B(1, 0, 1); STG_B(1, 1, 1); STG_A(1, 0, 1); STG_A(1, 1, 1);
  if (tid < BM) {
    const float* pr = Pin + (size_t)(t0 + tid) * 8;
    const float s = pr[0] + pr[1] + pr[2] + pr[3] + pr[4] + pr[5] + pr[6] + pr[7];
    invS[tid] = rsqrtf(s * (1.f / DD) + EPS_F);
  }
  VM_PRO();
  __builtin_amdgcn_s_barrier();

  for (int i = 0; i < NITER; ++i) {
    const int T2 = 2 * i + 2, T3 = 2 * i + 3;
    const bool s2 = T2 < NTILE, s3 = T3 < NTILE;
    PHASE(0, 0, 0, true,  true,  {}, {});
    PHASE(0, 0, 1, false, true,  {}, {});
    PHASE(0, 1, 1, true,  false, { if (s2) { STG_B(0, 0, T2); STG_B(0, 1, T2); } }, {});
    PHASE(0, 1, 0, false, false, { if (s2) STG_A(0, 0, T2); },
          { if (s2) VM_G3() else VM_ZERO(); });
    PHASE(1, 0, 0, true,  true,  { if (s2) STG_A(0, 1, T2); }, {});
    PHASE(1, 0, 1, false, true,  {}, {});
    PHASE(1, 1, 1, true,  false, { if (s3) { STG_B(1, 0, T3); STG_B(1, 1, T3); } }, {});
    PHASE(1, 1, 0, false, false, { if (s3) { STG_A(1, 0, T3); STG_A(1, 1, T3); } },
          { if (s3) VM_G7() else VM_ZERO(); });
  }
#undef PHASE
#undef RD_A
#undef RD_B
#undef STG_A
#undef STG_B
#undef VM_G3
#undef VM_G7
#undef VM_PRO
#undef VM_ZERO

#pragma unroll
  for (int mi = 0; mi < MI; ++mi) {
#pragma unroll
    for (int ni = 0; ni < 4; ++ni) {
      const int ocol = n0 + wn * 64 + ni * 16 + fr;
#pragma unroll
      for (int j = 0; j < 4; ++j) {
        const int lr = wm * HALF + mi * 16 + g * 4 + j;
        const size_t idx = (size_t)(t0 + lr) * ldc + ocol;
        C[idx] = invS[lr] * acc[mi][ni][j];
      }
    }
  }
}

// ---------------- lm_bf16 = bf16(lm * fnw) ----------------
__global__ void k_cvt(const float* __restrict__ in, const float* __restrict__ fnw,
                      unsigned short* __restrict__ out, int n4) {
  int i = blockIdx.x * blockDim.x + threadIdx.x;
  const int stride = gridDim.x * blockDim.x;
  for (; i < n4; i += stride) {
    const float4 v = ((const float4*)in)[i];
    const float4 w = ((const float4*)fnw)[i & 511];  // DD/4 = 512
    ushort4 o;
    o.x = f2bf(v.x * w.x); o.y = f2bf(v.y * w.y);
    o.z = f2bf(v.z * w.z); o.w = f2bf(v.w * w.w);
    ((ushort4*)out)[i] = o;
  }
}

extern "C" void kernel_launch(void* const* d_in, const int* in_sizes, int n_in,
                              void* d_out, int out_size, void* d_ws, size_t ws_size,
                              hipStream_t stream) {
  (void)in_sizes; (void)n_in; (void)out_size; (void)ws_size;
  const int* tokens = (const int*)d_in[0];
  const float* hr = (const float*)d_in[1];
  const float* hi = (const float*)d_in[2];
  const float* kar = (const float*)d_in[3];
  const float* kai = (const float*)d_in[4];
  const float* kbr = (const float*)d_in[5];
  const float* kbi = (const float*)d_in[6];
  const float* lscale = (const float*)d_in[7];
  const float* norm_w = (const float*)d_in[8];
  const float* embed = (const float*)d_in[9];
  const float* lm = (const float*)d_in[10];
  const float* fnw = (const float*)d_in[11];
  float* out = (float*)d_out;
  char* ws = (char*)d_ws;

  // ws: W' 192MB | P0,P1 (4096x8 f32 each) | hA bf16 16.7MB.
  // hB = first 16.7MB of d_out (dead before LM writes d_out; parity: 24 swaps).
  // lmb overlays W' (dead after last layer). Norm fused: W' carries norm_w,
  // lmb carries fnw, 1/rms applied in GEMM epilogues via P ping-pong.
  unsigned short* W = (unsigned short*)ws;
  float* P0 = (float*)(ws + 201326592);
  float* P1 = P0 + (size_t)NROWS * 8;
  unsigned short* hA = (unsigned short*)(ws + 201326592 + 262144);
  unsigned short* hB = (unsigned short*)d_out;
  unsigned short* lmb = W;

  hipMemsetAsync(P0, 0, (size_t)NROWS * 8 * sizeof(float), stream);
  k_gather<<<NROWS, 256, 0, stream>>>(tokens, embed, hA, P0);
  k_wrec<<<dim3(16, 32), 256, 0, stream>>>(hr, hi, kar, kai, kbr, kbi, lscale,
                                           norm_w, W);
  const unsigned short* cin = hA;
  unsigned short* cout = hB;
  const float* pin = P0;
  float* pout = P1;
  for (int l = 0; l < 12; ++l) {
    k_gemmL<0><<<256, 512, 0, stream>>>(cin, W + (size_t)(2 * l) * DD * DD, cout, pin, pout);
    { const unsigned short* tc = cin; cin = cout; cout = (unsigned short*)tc;
      const float* tp = pin; pin = pout; pout = (float*)tp; }
    k_gemmL<1><<<256, 512, 0, stream>>>(cin, W + (size_t)(2 * l + 1) * DD * DD, cout, pin, pout);
    { const unsigned short* tc = cin; cin = cout; cout = (unsigned short*)tc;
      const float* tp = pin; pin = pout; pout = (float*)tp; }
  }
  // after 24 swaps: cin == hA, pin == P0
  k_cvt<<<2048, 256, 0, stream>>>(lm, fnw, lmb, VOCAB_N * DD / 4);
  k_gemm8<256><<<2000, 512, 0, stream>>>(cin, lmb, out, VOCAB_N, 125, pin);
}

// Round 16
// 1832.808 us; speedup vs baseline: 1.3172x; 1.0377x over previous
//
#include <hip/hip_runtime.h>
#include <hip/hip_bf16.h>

#define DD 2048
#define NF 24
#define NROWS 4096
#define VOCAB_N 32000
#define EPS_F 1.1920929e-07f

typedef __attribute__((ext_vector_type(8))) __bf16 bf16x8;
typedef __attribute__((ext_vector_type(4))) float f32x4;

__device__ __forceinline__ unsigned short f2bf(float f) {
  union { float f; unsigned int u; } v; v.f = f;
  unsigned int r = v.u + 0x7fffu + ((v.u >> 16) & 1u);  // RNE
  return (unsigned short)(r >> 16);
}
__device__ __forceinline__ float bf2f(unsigned short u) {
  union { unsigned int i; float f; } v; v.i = ((unsigned int)u) << 16; return v.f;
}

__device__ __forceinline__ void gload_lds16(const void* g, void* l) {
  __builtin_amdgcn_global_load_lds(
      (const __attribute__((address_space(1))) void*)g,
      (__attribute__((address_space(3))) void*)l, 16, 0, 0);
}

// ---------------- gather: h0 = bf16(embed[tok]); P0[row][0] = sumsq ----------------
__global__ __launch_bounds__(256) void k_gather(const int* __restrict__ tok,
                                                const float* __restrict__ embed,
                                                unsigned short* __restrict__ h0,
                                                float* __restrict__ p0) {
  const int row = blockIdx.x, tid = threadIdx.x;
  const int t = tok[row];
  const float4* s = (const float4*)(embed + (size_t)t * DD);
  const float4 a = s[tid], b = s[tid + 256];
  float ss = a.x * a.x + a.y * a.y + a.z * a.z + a.w * a.w +
             b.x * b.x + b.y * b.y + b.z * b.z + b.w * b.w;
#pragma unroll
  for (int m = 32; m; m >>= 1) ss += __shfl_xor(ss, m);
  __shared__ float part[4];
  if ((tid & 63) == 0) part[tid >> 6] = ss;
  __syncthreads();
  if (tid == 0) p0[(size_t)row * 8] = part[0] + part[1] + part[2] + part[3];
  ushort4 o0, o1;
  o0.x = f2bf(a.x); o0.y = f2bf(a.y); o0.z = f2bf(a.z); o0.w = f2bf(a.w);
  o1.x = f2bf(b.x); o1.y = f2bf(b.y); o1.z = f2bf(b.z); o1.w = f2bf(b.w);
  ushort4* d = (ushort4*)(h0 + (size_t)row * DD);
  d[tid] = o0;
  d[tid + 256] = o1;
}

// ---------------- W reconstruction via MFMA, norm_w folded (r11) ----------------
__global__ __launch_bounds__(256) void k_wrec(
    const float* __restrict__ hr, const float* __restrict__ hi,
    const float* __restrict__ kar, const float* __restrict__ kai,
    const float* __restrict__ kbr, const float* __restrict__ kbi,
    const float* __restrict__ scale, const float* __restrict__ nw,
    unsigned short* __restrict__ W) {
  __shared__ float KAR[16][132], KAI[16][132];
  __shared__ float KBR[16][68], KBI[16][68];
  __shared__ unsigned short Wt[128][72];
  const int tid = threadIdx.x;
  const int lane = tid & 63, w = tid >> 6;
  const int fr = lane & 15, g = lane >> 4;
  const int o0 = blockIdx.x * 128, i0 = blockIdx.y * 64;

  float hrg[2][4][4], hig[2][4][4];
#pragma unroll
  for (int of = 0; of < 2; ++of)
#pragma unroll
    for (int jj = 0; jj < 4; ++jj) {
      const size_t orow = (size_t)(o0 + w * 32 + of * 16 + g * 4 + jj) * DD + i0;
#pragma unroll
      for (int fi = 0; fi < 4; ++fi) {
        hrg[of][jj][fi] = hr[orow + fi * 16 + fr];
        hig[of][jj][fi] = hi[orow + fi * 16 + fr];
      }
    }

  const int sr = tid >> 4;
  const int sca = (tid & 15) * 8;
  const int scb = (tid & 15) * 4;
  const int rlo = (g & 1) * 8;

  for (int f = 0; f < NF; ++f) {
    __syncthreads();
    {
      const size_t ga = ((size_t)f * 16 + sr) * DD;
      *(float4*)&KAR[sr][sca]     = *(const float4*)&kar[ga + o0 + sca];
      *(float4*)&KAR[sr][sca + 4] = *(const float4*)&kar[ga + o0 + sca + 4];
      *(float4*)&KAI[sr][sca]     = *(const float4*)&kai[ga + o0 + sca];
      *(float4*)&KAI[sr][sca + 4] = *(const float4*)&kai[ga + o0 + sca + 4];
      *(float4*)&KBR[sr][scb]     = *(const float4*)&kbr[ga + i0 + scb];
      *(float4*)&KBI[sr][scb]     = *(const float4*)&kbi[ga + i0 + scb];
    }
    __syncthreads();
    bf16x8 aPr[2], aPi[2], bF[4];
#pragma unroll
    for (int of = 0; of < 2; ++of) {
      const int oc = w * 32 + of * 16 + fr;
      union { bf16x8 v; unsigned short u[8]; } pu, pv;
#pragma unroll
      for (int j = 0; j < 8; ++j) {
        const float ka = KAR[rlo + j][oc];
        const float kb = KAI[rlo + j][oc];
        pu.u[j] = f2bf((g < 2) ? ka : kb);
        pv.u[j] = f2bf((g < 2) ? kb : -ka);
      }
      aPr[of] = pu.v; aPi[of] = pv.v;
    }
#pragma unroll
    for (int fi = 0; fi < 4; ++fi) {
      const int ic = fi * 16 + fr;
      union { bf16x8 v; unsigned short u[8]; } pb;
#pragma unroll
      for (int j = 0; j < 8; ++j) {
        const float vr = KBR[rlo + j][ic];
        const float vi = KBI[rlo + j][ic];
        pb.u[j] = f2bf((g < 2) ? vr : vi);
      }
      bF[fi] = pb.v;
    }
    const float sc = scale[f];
    float nwv[4];
#pragma unroll
    for (int fi = 0; fi < 4; ++fi) nwv[fi] = nw[(size_t)f * DD + i0 + fi * 16 + fr];
#pragma unroll
    for (int of = 0; of < 2; ++of)
#pragma unroll
      for (int fi = 0; fi < 4; ++fi) {
        const f32x4 z = (f32x4){0.f, 0.f, 0.f, 0.f};
        const f32x4 cr = __builtin_amdgcn_mfma_f32_16x16x32_bf16(aPr[of], bF[fi], z, 0, 0, 0);
        const f32x4 ci = __builtin_amdgcn_mfma_f32_16x16x32_bf16(aPi[of], bF[fi], z, 0, 0, 0);
#pragma unroll
        for (int jj = 0; jj < 4; ++jj) {
          const float wv = (hrg[of][jj][fi] * cr[jj] - hig[of][jj][fi] * ci[jj]) * sc * nwv[fi];
          Wt[w * 32 + of * 16 + g * 4 + jj][fi * 16 + fr] = f2bf(wv);
        }
      }
    __syncthreads();
    {
      const int r = tid >> 1, hh = tid & 1;
      unsigned short* dst = W + ((size_t)f * DD + o0 + r) * DD + i0 + hh * 32;
#pragma unroll
      for (int qq = 0; qq < 4; ++qq)
        *(uint4*)(dst + qq * 8) = *(const uint4*)&Wt[r][hh * 32 + qq * 8];
    }
  }
}

// ---------------- layer GEMM: ring-3, one barrier-pair/K-tile (r15) + A-resident map ----------------
// Mapping m-slow/n-fast: XCD k's 32 contiguous swz give t0 = 4 A-slabs (2MB,
// L2-resident) x n0 = all 8 W-panels (8MB, L3-shared). Mirrors the r14 LM fix:
// A is the operand that must live in L2; W streams through L3.
template <int ACT>
__global__ __launch_bounds__(512, 2) void k_gemmL(const unsigned short* __restrict__ Hin,
                                                  const unsigned short* __restrict__ B,
                                                  unsigned short* __restrict__ Hout,
                                                  const float* __restrict__ Pin,
                                                  float* __restrict__ Pout) {
  constexpr int NTILE = DD / 64;  // 32
  __shared__ unsigned short lsA[3][8192];    // [slot][128 rows][64 k]
  __shared__ unsigned short lsB[3][16384];   // [slot][256 rows][64 k]
  __shared__ float invS[128];
  __shared__ float rsum[128];
  const int tid = threadIdx.x;
  const int lane = tid & 63, wave = tid >> 6;
  const int wm = wave >> 2, wn = wave & 3;
  const int bid = blockIdx.x;
  const int swz = (bid & 7) * 32 + (bid >> 3);   // 256 blocks: XCD-contig
  const int t0 = (swz >> 3) * 128;               // m slow: 4 A-slabs per XCD
  const int n0 = (swz & 7) * 256;                // n fast: all 8 panels per XCD
  const unsigned short* Ab = Hin + (size_t)t0 * DD;
  const unsigned short* Bb = B + (size_t)n0 * DD;
  const int fr = lane & 15, g = lane >> 4;
  const int srow8 = tid >> 3, sslot = tid & 7;

#define LSTG_A(slot, tile)                                                          \
  { _Pragma("unroll")                                                               \
    for (int l = 0; l < 2; ++l) {                                                   \
      const int rt = l * 64 + srow8;                                                \
      gload_lds16(Ab + (size_t)rt * DD + (tile) * 64 + ((sslot ^ (rt & 7)) << 3),   \
                  &lsA[slot][rt * 64 + sslot * 8]);                                 \
    } }
#define LSTG_B(slot, h, tile)                                                       \
  { _Pragma("unroll")                                                               \
    for (int l = 0; l < 2; ++l) {                                                   \
      const int rt = (h) * 128 + l * 64 + srow8;                                    \
      gload_lds16(Bb + (size_t)rt * DD + (tile) * 64 + ((sslot ^ (rt & 7)) << 3),   \
                  &lsB[slot][rt * 64 + sslot * 8]);                                 \
    } }
#define LRD_A(slot, mi, ks)                                                         \
  (*(const bf16x8*)&lsA[slot][(wm * 64 + (mi) * 16 + fr) * 64 +                     \
                              ((((ks) * 4 + g) ^ ((wm * 64 + (mi) * 16 + fr) & 7)) << 3)])
#define LRD_B(slot, ni, ks)                                                         \
  (*(const bf16x8*)&lsB[slot][(wn * 64 + (ni) * 16 + fr) * 64 +                     \
                              ((((ks) * 4 + g) ^ ((wn * 64 + (ni) * 16 + fr) & 7)) << 3)])

  f32x4 acc[4][4];
#pragma unroll
  for (int i = 0; i < 4; ++i)
#pragma unroll
    for (int j = 0; j < 4; ++j) acc[i][j] = (f32x4){0.f, 0.f, 0.f, 0.f};

  bf16x8 aF[4][2], bF[4][2];

#define LTILE(t, sc, sp)                                                            \
  {                                                                                 \
    const bool st = (t) + 2 < NTILE;                                                \
    _Pragma("unroll")                                                               \
    for (int mi = 0; mi < 4; ++mi) { _Pragma("unroll")                              \
      for (int ks = 0; ks < 2; ++ks) aF[mi][ks] = LRD_A(sc, mi, ks); }              \
    _Pragma("unroll")                                                               \
    for (int ni = 0; ni < 4; ++ni) { _Pragma("unroll")                              \
      for (int ks = 0; ks < 2; ++ks) bF[ni][ks] = LRD_B(sc, ni, ks); }              \
    if (st) { LSTG_A(sp, (t) + 2); LSTG_B(sp, 0, (t) + 2); LSTG_B(sp, 1, (t) + 2); }\
    if (st) asm volatile("s_waitcnt vmcnt(6)" ::: "memory");                        \
    else    asm volatile("s_waitcnt vmcnt(0)" ::: "memory");                        \
    __builtin_amdgcn_s_barrier();                                                   \
    asm volatile("s_waitcnt lgkmcnt(0)" ::: "memory");                              \
    __builtin_amdgcn_s_setprio(1);                                                  \
    _Pragma("unroll")                                                               \
    for (int ks = 0; ks < 2; ++ks) { _Pragma("unroll")                              \
      for (int mi = 0; mi < 4; ++mi) { _Pragma("unroll")                            \
        for (int ni = 0; ni < 4; ++ni)                                              \
          acc[mi][ni] = __builtin_amdgcn_mfma_f32_16x16x32_bf16(                    \
              aF[mi][ks], bF[ni][ks], acc[mi][ni], 0, 0, 0); } }                    \
    __builtin_amdgcn_s_setprio(0);                                                  \
    __builtin_amdgcn_s_barrier();                                                   \
  }

  LSTG_A(0, 0); LSTG_B(0, 0, 0); LSTG_B(0, 1, 0);
  LSTG_A(1, 1); LSTG_B(1, 0, 1); LSTG_B(1, 1, 1);
  // fused-norm prologue: inv per row from 8 panel partials
  if (tid < 128) {
    const float* pr = Pin + (size_t)(t0 + tid) * 8;
    const float s = pr[0] + pr[1] + pr[2] + pr[3] + pr[4] + pr[5] + pr[6] + pr[7];
    invS[tid] = rsqrtf(s * (1.f / DD) + EPS_F);
  }
  asm volatile("s_waitcnt vmcnt(6)" ::: "memory");
  __builtin_amdgcn_s_barrier();

  for (int tb = 0; tb < 30; tb += 3) {
    LTILE(tb, 0, 2);
    LTILE(tb + 1, 1, 0);
    LTILE(tb + 2, 2, 1);
  }
  LTILE(30, 0, 2);
  LTILE(31, 1, 0);
#undef LTILE
#undef LRD_A
#undef LRD_B
#undef LSTG_A
#undef LSTG_B

  // epilogue: apply inv, residual-add into Hout, per-row sumsq partial -> Pout
  __syncthreads();
  if (tid < 128) rsum[tid] = 0.f;
  __syncthreads();
  const int panel = n0 >> 8;
#pragma unroll
  for (int mi = 0; mi < 4; ++mi) {
#pragma unroll
    for (int j = 0; j < 4; ++j) {
      const int lr = wm * 64 + mi * 16 + g * 4 + j;
      const float iv = invS[lr];
      float racc = 0.f;
#pragma unroll
      for (int ni = 0; ni < 4; ++ni) {
        const size_t idx = (size_t)(t0 + lr) * DD + (n0 + wn * 64 + ni * 16 + fr);
        const float v = acc[mi][ni][j] * iv;
        const float old = bf2f(Hin[idx]);
        float nv;
        if (ACT == 0) nv = old + v;
        else          nv = old + v / (1.f + __expf(-v));
        Hout[idx] = f2bf(nv);
        racc += nv * nv;
      }
      racc += __shfl_xor(racc, 1);
      racc += __shfl_xor(racc, 2);
      racc += __shfl_xor(racc, 4);
      racc += __shfl_xor(racc, 8);
      if (fr == 0) atomicAdd(&rsum[lr], racc);
    }
  }
  __syncthreads();
  if (tid < 128) Pout[(size_t)(t0 + tid) * 8 + panel] = rsum[tid];
}

// ---------------- 8-phase GEMM for LM head (r14, frozen) ----------------
template <int BM>
__global__ __launch_bounds__(512, 2) void k_gemm8(const unsigned short* __restrict__ A,
                                                  const unsigned short* __restrict__ B,
                                                  float* __restrict__ C, const int ldc,
                                                  const int npan,
                                                  const float* __restrict__ Pin) {
  constexpr int HALF = BM / 2;
  constexpr int MI = BM / 32;
  constexpr int MQ = MI / 2;
  constexpr int A_LOADS = HALF / 64;
  constexpr int NTILE = DD / 64;
  constexpr int NITER = NTILE / 2;

  __shared__ unsigned short lsA[2][BM * 64];
  __shared__ unsigned short lsB[2][256 * 64];
  __shared__ float invS[BM];

  const int tid = threadIdx.x;
  const int lane = tid & 63, wave = tid >> 6;
  const int wm = wave >> 2, wn = wave & 3;
  const int bid = blockIdx.x;
  const int swz = (bid & 7) * (gridDim.x >> 3) + (bid >> 3);
  const int t0 = (swz / npan) * BM;   // m slow within XCD
  const int n0 = (swz % npan) * 256;  // n fast within XCD
  const unsigned short* Ab = A + (size_t)t0 * DD;
  const unsigned short* Bb = B + (size_t)n0 * DD;
  const int fr = lane & 15, g = lane >> 4;
  const int srow8 = tid >> 3, sslot = tid & 7;

#define STG_A(buf, h, tile)                                                         \
  { _Pragma("unroll")                                                               \
    for (int l = 0; l < A_LOADS; ++l) {                                             \
      const int rt = (h) * HALF + l * 64 + srow8;                                   \
      gload_lds16(Ab + (size_t)rt * DD + (tile) * 64 + ((sslot ^ (rt & 7)) << 3),   \
                  &lsA[buf][rt * 64 + sslot * 8]);                                  \
    } }
#define STG_B(buf, h, tile)                                                         \
  { _Pragma("unroll")                                                               \
    for (int l = 0; l < 2; ++l) {                                                   \
      const int rt = (h) * 128 + l * 64 + srow8;                                    \
      gload_lds16(Bb + (size_t)rt * DD + (tile) * 64 + ((sslot ^ (rt & 7)) << 3),   \
                  &lsB[buf][rt * 64 + sslot * 8]);                                  \
    } }
#define VM_G3()                                                                     \
  { if constexpr (BM == 256) asm volatile("s_waitcnt vmcnt(6)" ::: "memory");       \
    else                     asm volatile("s_waitcnt vmcnt(5)" ::: "memory"); }
#define VM_G7()                                                                     \
  { if constexpr (BM == 256) asm volatile("s_waitcnt vmcnt(8)" ::: "memory");       \
    else                     asm volatile("s_waitcnt vmcnt(6)" ::: "memory"); }
#define VM_PRO()                                                                    \
  { if constexpr (BM == 256) asm volatile("s_waitcnt vmcnt(8)" ::: "memory");       \
    else                     asm volatile("s_waitcnt vmcnt(6)" ::: "memory"); }
#define VM_ZERO() asm volatile("s_waitcnt vmcnt(0)" ::: "memory")

  f32x4 acc[MI][4];
#pragma unroll
  for (int i = 0; i < MI; ++i)
#pragma unroll
    for (int j = 0; j < 4; ++j) acc[i][j] = (f32x4){0.f, 0.f, 0.f, 0.f};

  bf16x8 aF[MQ][2];
  bf16x8 bF[2][2][2];

#define RD_A(buf, mi, ks)                                                           \
  (*(const bf16x8*)&lsA[buf][(wm * HALF + (mi) * 16 + fr) * 64 +                    \
                             ((((ks) * 4 + g) ^ ((wm * HALF + (mi) * 16 + fr) & 7)) << 3)])
#define RD_B(buf, ni, ks)                                                           \
  (*(const bf16x8*)&lsB[buf][(wn * 64 + (ni) * 16 + fr) * 64 +                      \
                             ((((ks) * 4 + g) ^ ((wn * 64 + (ni) * 16 + fr) & 7)) << 3)])

#define PHASE(buf, mh, nh, LA, LB, STAGES, VMK)                                     \
  {                                                                                 \
    if (LA) { _Pragma("unroll")                                                     \
      for (int q = 0; q < MQ; ++q) { _Pragma("unroll")                              \
        for (int ks = 0; ks < 2; ++ks) aF[q][ks] = RD_A(buf, (mh) * MQ + q, ks); } }\
    if (LB) { _Pragma("unroll")                                                     \
      for (int q = 0; q < 2; ++q) { _Pragma("unroll")                               \
        for (int ks = 0; ks < 2; ++ks) bF[nh][q][ks] = RD_B(buf, (nh) * 2 + q, ks); } } \
    STAGES;                                                                         \
    VMK;                                                                            \
    __builtin_amdgcn_s_barrier();                                                   \
    asm volatile("s_waitcnt lgkmcnt(0)" ::: "memory");                              \
    __builtin_amdgcn_s_setprio(1);                                                  \
    _Pragma("unroll")                                                               \
    for (int ks = 0; ks < 2; ++ks) { _Pragma("unroll")                              \
      for (int q = 0; q < MQ; ++q) { _Pragma("unroll")                              \
        for (int nq = 0; nq < 2; ++nq)                                              \
          acc[(mh) * MQ + q][(nh) * 2 + nq] = __builtin_amdgcn_mfma_f32_16x16x32_bf16( \
              aF[q][ks], bF[nh][nq][ks], acc[(mh) * MQ + q][(nh) * 2 + nq], 0, 0, 0); } } \
    __builtin_amdgcn_s_setprio(0);                                                  \
    __builtin_amdgcn_s_barrier();                                                   \
  }

  STG_B(0, 0, 0); STG_B(0, 1, 0); STG_A(0, 0, 0); STG_A(0, 1, 0);
  STG_B(1, 0, 1); STG_B(1, 1, 1); STG_A(1, 0, 1); STG_A(1, 1, 1);
  if (tid < BM) {
    const float* pr = Pin + (size_t)(t0 + tid) * 8;
    const float s = pr[0] + pr[1] + pr[2] + pr[3] + pr[4] + pr[5] + pr[6] + pr[7];
    invS[tid] = rsqrtf(s * (1.f / DD) + EPS_F);
  }
  VM_PRO();
  __builtin_amdgcn_s_barrier();

  for (int i = 0; i < NITER; ++i) {
    const int T2 = 2 * i + 2, T3 = 2 * i + 3;
    const bool s2 = T2 < NTILE, s3 = T3 < NTILE;
    PHASE(0, 0, 0, true,  true,  {}, {});
    PHASE(0, 0, 1, false, true,  {}, {});
    PHASE(0, 1, 1, true,  false, { if (s2) { STG_B(0, 0, T2); STG_B(0, 1, T2); } }, {});
    PHASE(0, 1, 0, false, false, { if (s2) STG_A(0, 0, T2); },
          { if (s2) VM_G3() else VM_ZERO(); });
    PHASE(1, 0, 0, true,  true,  { if (s2) STG_A(0, 1, T2); }, {});
    PHASE(1, 0, 1, false, true,  {}, {});
    PHASE(1, 1, 1, true,  false, { if (s3) { STG_B(1, 0, T3); STG_B(1, 1, T3); } }, {});
    PHASE(1, 1, 0, false, false, { if (s3) { STG_A(1, 0, T3); STG_A(1, 1, T3); } },
          { if (s3) VM_G7() else VM_ZERO(); });
  }
#undef PHASE
#undef RD_A
#undef RD_B
#undef STG_A
#undef STG_B
#undef VM_G3
#undef VM_G7
#undef VM_PRO
#undef VM_ZERO

#pragma unroll
  for (int mi = 0; mi < MI; ++mi) {
#pragma unroll
    for (int ni = 0; ni < 4; ++ni) {
      const int ocol = n0 + wn * 64 + ni * 16 + fr;
#pragma unroll
      for (int j = 0; j < 4; ++j) {
        const int lr = wm * HALF + mi * 16 + g * 4 + j;
        const size_t idx = (size_t)(t0 + lr) * ldc + ocol;
        C[idx] = invS[lr] * acc[mi][ni][j];
      }
    }
  }
}

// ---------------- lm_bf16 = bf16(lm * fnw) ----------------
__global__ void k_cvt(const float* __restrict__ in, const float* __restrict__ fnw,
                      unsigned short* __restrict__ out, int n4) {
  int i = blockIdx.x * blockDim.x + threadIdx.x;
  const int stride = gridDim.x * blockDim.x;
  for (; i < n4; i += stride) {
    const float4 v = ((const float4*)in)[i];
    const float4 w = ((const float4*)fnw)[i & 511];  // DD/4 = 512
    ushort4 o;
    o.x = f2bf(v.x * w.x); o.y = f2bf(v.y * w.y);
    o.z = f2bf(v.z * w.z); o.w = f2bf(v.w * w.w);
    ((ushort4*)out)[i] = o;
  }
}

extern "C" void kernel_launch(void* const* d_in, const int* in_sizes, int n_in,
                              void* d_out, int out_size, void* d_ws, size_t ws_size,
                              hipStream_t stream) {
  (void)in_sizes; (void)n_in; (void)out_size; (void)ws_size;
  const int* tokens = (const int*)d_in[0];
  const float* hr = (const float*)d_in[1];
  const float* hi = (const float*)d_in[2];
  const float* kar = (const float*)d_in[3];
  const float* kai = (const float*)d_in[4];
  const float* kbr = (const float*)d_in[5];
  const float* kbi = (const float*)d_in[6];
  const float* lscale = (const float*)d_in[7];
  const float* norm_w = (const float*)d_in[8];
  const float* embed = (const float*)d_in[9];
  const float* lm = (const float*)d_in[10];
  const float* fnw = (const float*)d_in[11];
  float* out = (float*)d_out;
  char* ws = (char*)d_ws;

  // ws: W' 192MB | P0,P1 (4096x8 f32 each) | hA bf16 16.7MB.
  // hB = first 16.7MB of d_out (dead before LM writes d_out; parity: 24 swaps).
  // lmb overlays W' (dead after last layer). Norm fused: W' carries norm_w,
  // lmb carries fnw, 1/rms applied in GEMM epilogues via P ping-pong.
  unsigned short* W = (unsigned short*)ws;
  float* P0 = (float*)(ws + 201326592);
  float* P1 = P0 + (size_t)NROWS * 8;
  unsigned short* hA = (unsigned short*)(ws + 201326592 + 262144);
  unsigned short* hB = (unsigned short*)d_out;
  unsigned short* lmb = W;

  hipMemsetAsync(P0, 0, (size_t)NROWS * 8 * sizeof(float), stream);
  k_gather<<<NROWS, 256, 0, stream>>>(tokens, embed, hA, P0);
  k_wrec<<<dim3(16, 32), 256, 0, stream>>>(hr, hi, kar, kai, kbr, kbi, lscale,
                                           norm_w, W);
  const unsigned short* cin = hA;
  unsigned short* cout = hB;
  const float* pin = P0;
  float* pout = P1;
  for (int l = 0; l < 12; ++l) {
    k_gemmL<0><<<256, 512, 0, stream>>>(cin, W + (size_t)(2 * l) * DD * DD, cout, pin, pout);
    { const unsigned short* tc = cin; cin = cout; cout = (unsigned short*)tc;
      const float* tp = pin; pin = pout; pout = (float*)tp; }
    k_gemmL<1><<<256, 512, 0, stream>>>(cin, W + (size_t)(2 * l + 1) * DD * DD, cout, pin, pout);
    { const unsigned short* tc = cin; cin = cout; cout = (unsigned short*)tc;
      const float* tp = pin; pin = pout; pout = (float*)tp; }
  }
  // after 24 swaps: cin == hA, pin == P0
  k_cvt<<<2048, 256, 0, stream>>>(lm, fnw, lmb, VOCAB_N * DD / 4);
  k_gemm8<256><<<2000, 512, 0, stream>>>(cin, lmb, out, VOCAB_N, 125, pin);
}